// Round 9
// baseline (329.040 us; speedup 1.0000x reference)
//
#include <hip/hip_runtime.h>

// Problem sizes (match reference)
#define NS0 300000
#define ND0 50000
#define NE0 800000
#define NS1 50000
#define ND1 8192
#define NE1 131072
#define IN_F 256
#define HID_F 128
#define SLOTS 64   // bucket-CSR capacity; indeg ~ Poisson(16), P(>=64) ~ 1e-19
#define NTILE (NS0 / 16)  // 18750 row-tiles for the dense GEMM

typedef __attribute__((ext_vector_type(8))) _Float16 half8_t;
typedef __attribute__((ext_vector_type(2))) _Float16 half2_t;
typedef __attribute__((ext_vector_type(4))) float f32x4;

// Workspace layout (4-byte words), all 16B-aligned:
//   outdeg0i [NS0]            @ 0
//   outdeg1i [NS1]            @ 300000
//   cnt0     [ND0]            @ 350000
//   cnt1     [ND1]            @ 400000     -- zeroed range ends 408192 (1.63 MB)
//   edge0    [ND0*SLOTS*2]    @ 408192     ends 6808192   (int2 (src, ew-bits))
//   edge1    [ND1*SLOTS*2]    @ 6808192    ends 7856768
//   h1       [ND0*HID_F f32]  @ 7856768    ends 14256768  (pre-scaled by rsqrt(outdeg1))
//   w1t      [128*256 fp16]   @ 14256768   ends 14273152  (W1 transposed, fp16)
//   g        [NS0*128 fp16]   @ 14273152   ends 33473152  (134 MB total)
#define OFF_OUTDEG0I 0
#define OFF_OUTDEG1I 300000
#define OFF_CNT0     350000
#define OFF_CNT1     400000
#define ZERO_WORDS   408192
#define OFF_EDGE0    408192
#define OFF_EDGE1    6808192
#define OFF_H1       7856768
#define OFF_W1T      14256768
#define OFF_G        14273152

// ----------------------------------------------------------- zero counters
__global__ __launch_bounds__(256) void k_zero(int4* __restrict__ p, int n4) {
  int i = blockIdx.x * 256 + threadIdx.x;
  int s = gridDim.x * 256;
  for (; i < n4; i += s) p[i] = make_int4(0, 0, 0, 0);
}

// ------------------------- W1 [256][128] f32 -> w1t [128][256] f16 (tiny)
__global__ __launch_bounds__(256) void k_prep(
    const float* __restrict__ W1, _Float16* __restrict__ w1t) {
  int i = blockIdx.x * 256 + threadIdx.x;
  int s = gridDim.x * 256;
  for (; i < IN_F * HID_F; i += s) {
    int k = i >> 7, n = i & 127;
    w1t[n * 256 + k] = (_Float16)W1[i];
  }
}

// ------------------- fused degree-histogram + bucket scatter (single pass)
__global__ __launch_bounds__(256) void k_build(
    const int* __restrict__ src0, const int* __restrict__ dst0,
    const float* __restrict__ ew0, int* __restrict__ outdeg0,
    int* __restrict__ cnt0, int2* __restrict__ edge0,
    const int* __restrict__ src1, const int* __restrict__ dst1,
    const float* __restrict__ ew1, int* __restrict__ outdeg1,
    int* __restrict__ cnt1, int2* __restrict__ edge1) {
  int tid = blockIdx.x * blockDim.x + threadIdx.x;
  int stride = gridDim.x * blockDim.x;
  for (int i = tid; i < NE0; i += stride) {
    int s = src0[i];
    int d = dst0[i];
    float w = ew0[i];
    atomicAdd(&outdeg0[s], 1);
    int slot = atomicAdd(&cnt0[d], 1);
    if (slot < SLOTS) edge0[d * SLOTS + slot] = make_int2(s, __float_as_int(w));
  }
  for (int i = tid; i < NE1; i += stride) {
    int s = src1[i];
    int d = dst1[i];
    float w = ew1[i];
    atomicAdd(&outdeg1[s], 1);
    int slot = atomicAdd(&cnt1[d], 1);
    if (slot < SLOTS) edge1[d * SLOTS + slot] = make_int2(s, __float_as_int(w));
  }
}

// ---------------- dense GEMM: g = (x * rsqrt(outdeg0)) @ W1, fp16 in/out,
// fp32 MFMA accumulate. Block = 4 waves; wave wv owns cols [32wv, 32wv+32);
// block processes 16 rows/tile, grid-strides over 18750 tiles.
// A-frag: lane holds x[row = l&15][k = kb*32 + (l>>4)*8 + j] (converted in-reg)
// B-frag: lane holds W1[k = kb*32 + (l>>4)*8 + j][n = 32wv + 16c + (l&15)]
// (same k-mapping for A and B; any hw k-permutation cancels).
__global__ __launch_bounds__(256) void k_gemm1(
    const float* __restrict__ x, const int* __restrict__ outdeg0,
    const _Float16* __restrict__ w1t, _Float16* __restrict__ g) {
  __shared__ _Float16 outT[16 * 128];
  const int wv = threadIdx.x >> 6;
  const int lane = threadIdx.x & 63;
  const int m = lane & 15;
  const int grp = lane >> 4;

  // persistent B fragments: 2 col-tiles x 8 K-steps = 64 VGPR
  half8_t bfrag[2][8];
#pragma unroll
  for (int c = 0; c < 2; ++c)
#pragma unroll
    for (int kb = 0; kb < 8; ++kb)
      bfrag[c][kb] = *reinterpret_cast<const half8_t*>(
          w1t + (size_t)(32 * wv + 16 * c + m) * 256 + kb * 32 + grp * 8);

  for (int tile = blockIdx.x; tile < NTILE; tile += gridDim.x) {
    const int row = tile * 16 + m;
    const float sc = rsqrtf(fmaxf((float)outdeg0[row], 1.0f));
    f32x4 acc0 = {0.f, 0.f, 0.f, 0.f};
    f32x4 acc1 = {0.f, 0.f, 0.f, 0.f};
    const float* xr = x + (size_t)row * IN_F + grp * 8;
#pragma unroll
    for (int kb = 0; kb < 8; ++kb) {
      const float4 xa = *reinterpret_cast<const float4*>(xr + kb * 32);
      const float4 xb = *reinterpret_cast<const float4*>(xr + kb * 32 + 4);
      half8_t af;
      af[0] = (_Float16)(xa.x * sc);
      af[1] = (_Float16)(xa.y * sc);
      af[2] = (_Float16)(xa.z * sc);
      af[3] = (_Float16)(xa.w * sc);
      af[4] = (_Float16)(xb.x * sc);
      af[5] = (_Float16)(xb.y * sc);
      af[6] = (_Float16)(xb.z * sc);
      af[7] = (_Float16)(xb.w * sc);
      acc0 = __builtin_amdgcn_mfma_f32_16x16x32_f16(af, bfrag[0][kb], acc0, 0, 0, 0);
      acc1 = __builtin_amdgcn_mfma_f32_16x16x32_f16(af, bfrag[1][kb], acc1, 0, 0, 0);
    }
    // C/D layout (verified): col = lane&15, row = 4*(lane>>4) + reg
#pragma unroll
    for (int r = 0; r < 4; ++r) {
      outT[(4 * grp + r) * 128 + 32 * wv + m]      = (_Float16)acc0[r];
      outT[(4 * grp + r) * 128 + 32 * wv + 16 + m] = (_Float16)acc1[r];
    }
    __syncthreads();
    const int r2 = threadIdx.x >> 4;
    const int c2 = threadIdx.x & 15;
    *reinterpret_cast<half8_t*>(g + (size_t)(tile * 16 + r2) * 128 + c2 * 8) =
        *reinterpret_cast<const half8_t*>(outT + r2 * 128 + c2 * 8);
    __syncthreads();
  }
}

// ---------------- layer-1 aggregation over g (fp16, 77 MB, L3-resident):
// h1[d] = relu(rsqrt(indeg)*sum ew*g[src] + b1) * rsqrt(outdeg1[d])
// One wave per 2 dst rows; lane holds dims (2*lane, 2*lane+1) of 128.
__global__ __launch_bounds__(256) void k_gather1(
    const _Float16* __restrict__ g, const int* __restrict__ cnt,
    const int2* __restrict__ edge, const int* __restrict__ outdeg1,
    const float* __restrict__ b1, float* __restrict__ h1) {
  const int w = (blockIdx.x * 256 + threadIdx.x) >> 6;
  const int lane = threadIdx.x & 63;
  if (w >= ND0 / 2) return;
  const float2 bv = *reinterpret_cast<const float2*>(b1 + 2 * lane);
#pragma unroll
  for (int rr = 0; rr < 2; ++rr) {
    const int row = w * 2 + rr;
    const int deg = min(cnt[row], SLOTS);
    const int2* ep = edge + (size_t)row * SLOTS;
    float2 acc = make_float2(0.f, 0.f);
    int e = 0;
    for (; e + 4 <= deg; e += 4) {
      int4 q0 = *reinterpret_cast<const int4*>(ep + e);
      int4 q1 = *reinterpret_cast<const int4*>(ep + e + 2);
      half2_t v0 = *reinterpret_cast<const half2_t*>(g + (size_t)q0.x * 128 + 2 * lane);
      half2_t v1 = *reinterpret_cast<const half2_t*>(g + (size_t)q0.z * 128 + 2 * lane);
      half2_t v2 = *reinterpret_cast<const half2_t*>(g + (size_t)q1.x * 128 + 2 * lane);
      half2_t v3 = *reinterpret_cast<const half2_t*>(g + (size_t)q1.z * 128 + 2 * lane);
      float c0 = __int_as_float(q0.y), c1 = __int_as_float(q0.w);
      float c2 = __int_as_float(q1.y), c3 = __int_as_float(q1.w);
      acc.x = fmaf(c0, (float)v0[0], acc.x); acc.y = fmaf(c0, (float)v0[1], acc.y);
      acc.x = fmaf(c1, (float)v1[0], acc.x); acc.y = fmaf(c1, (float)v1[1], acc.y);
      acc.x = fmaf(c2, (float)v2[0], acc.x); acc.y = fmaf(c2, (float)v2[1], acc.y);
      acc.x = fmaf(c3, (float)v3[0], acc.x); acc.y = fmaf(c3, (float)v3[1], acc.y);
    }
    for (; e < deg; ++e) {
      int2 p = ep[e];
      half2_t v = *reinterpret_cast<const half2_t*>(g + (size_t)p.x * 128 + 2 * lane);
      float c = __int_as_float(p.y);
      acc.x = fmaf(c, (float)v[0], acc.x); acc.y = fmaf(c, (float)v[1], acc.y);
    }
    const float sc = rsqrtf(fmaxf((float)deg, 1.0f));
    const float s1 = rsqrtf(fmaxf((float)outdeg1[row], 1.0f));
    float2 o;
    o.x = fmaxf(fmaf(acc.x, sc, bv.x), 0.0f) * s1;
    o.y = fmaxf(fmaf(acc.y, sc, bv.y), 0.0f) * s1;
    *reinterpret_cast<float2*>(h1 + (size_t)row * 128 + 2 * lane) = o;
  }
}

#define FMA2(acc, c, v)        \
  acc.x = fmaf(c, v.x, acc.x); \
  acc.y = fmaf(c, v.y, acc.y);

// --------------------------------------------- fused gather + GEMM, layer 2
// h1 already carries rsqrt(outdeg1); coef = ew only. h1 is 25.6MB, L3-resident.
__global__ __launch_bounds__(256) void k_layer2(
    const float* __restrict__ h1, const int* __restrict__ cnt,
    const int2* __restrict__ edge, const float* __restrict__ W2,
    const float* __restrict__ b2, float* __restrict__ out) {
  __shared__ float arow[8][HID_F];
  const int t = blockIdx.x;
  const int wv = threadIdx.x >> 6;
  const int lane = threadIdx.x & 63;

#pragma unroll
  for (int rr = 0; rr < 2; ++rr) {
    const int row = t * 8 + wv * 2 + rr;
    const int deg = min(cnt[row], SLOTS);
    const int2* ep = edge + (size_t)row * SLOTS;
    float2 acc = make_float2(0.f, 0.f);
    int e = 0;
    for (; e + 4 <= deg; e += 4) {
      int4 q0 = *reinterpret_cast<const int4*>(ep + e);
      int4 q1 = *reinterpret_cast<const int4*>(ep + e + 2);
      float2 v0 = *reinterpret_cast<const float2*>(h1 + (size_t)q0.x * HID_F + lane * 2);
      float2 v1 = *reinterpret_cast<const float2*>(h1 + (size_t)q0.z * HID_F + lane * 2);
      float2 v2 = *reinterpret_cast<const float2*>(h1 + (size_t)q1.x * HID_F + lane * 2);
      float2 v3 = *reinterpret_cast<const float2*>(h1 + (size_t)q1.z * HID_F + lane * 2);
      FMA2(acc, __int_as_float(q0.y), v0);
      FMA2(acc, __int_as_float(q0.w), v1);
      FMA2(acc, __int_as_float(q1.y), v2);
      FMA2(acc, __int_as_float(q1.w), v3);
    }
    for (; e < deg; ++e) {
      int2 p = ep[e];
      float2 v = *reinterpret_cast<const float2*>(h1 + (size_t)p.x * HID_F + lane * 2);
      FMA2(acc, __int_as_float(p.y), v);
    }
    const float sc = rsqrtf(fmaxf((float)deg, 1.0f));
    *reinterpret_cast<float2*>(&arow[wv * 2 + rr][lane * 2]) =
        make_float2(acc.x * sc, acc.y * sc);
  }
  __syncthreads();

  const int j = threadIdx.x & 127;
  const int rg = threadIdx.x >> 7;
  float a0 = 0.f, a1 = 0.f, a2 = 0.f, a3 = 0.f;
  const float* wj = W2 + j;
#pragma unroll 8
  for (int k = 0; k < HID_F; ++k) {
    const float wvv = wj[(size_t)k * 128];
    a0 = fmaf(arow[rg * 4 + 0][k], wvv, a0);
    a1 = fmaf(arow[rg * 4 + 1][k], wvv, a1);
    a2 = fmaf(arow[rg * 4 + 2][k], wvv, a2);
    a3 = fmaf(arow[rg * 4 + 3][k], wvv, a3);
  }
  const float bj = b2[j];
  const int row0 = t * 8 + rg * 4;
  out[(size_t)(row0 + 0) * 128 + j] = fmaxf(a0 + bj, 0.0f);
  out[(size_t)(row0 + 1) * 128 + j] = fmaxf(a1 + bj, 0.0f);
  out[(size_t)(row0 + 2) * 128 + j] = fmaxf(a2 + bj, 0.0f);
  out[(size_t)(row0 + 3) * 128 + j] = fmaxf(a3 + bj, 0.0f);
}

extern "C" void kernel_launch(void* const* d_in, const int* in_sizes, int n_in,
                              void* d_out, int out_size, void* d_ws, size_t ws_size,
                              hipStream_t stream) {
  const float* x    = (const float*)d_in[0];
  const int*   src0 = (const int*)d_in[1];
  const int*   dst0 = (const int*)d_in[2];
  const float* ew0  = (const float*)d_in[3];
  const int*   src1 = (const int*)d_in[4];
  const int*   dst1 = (const int*)d_in[5];
  const float* ew1  = (const float*)d_in[6];
  const float* W1   = (const float*)d_in[7];
  const float* b1   = (const float*)d_in[8];
  const float* W2   = (const float*)d_in[9];
  const float* b2   = (const float*)d_in[10];
  float* out = (float*)d_out;

  int*   wsi = (int*)d_ws;
  float* wsf = (float*)d_ws;
  int* outdeg0 = wsi + OFF_OUTDEG0I;
  int* outdeg1 = wsi + OFF_OUTDEG1I;
  int* cnt0    = wsi + OFF_CNT0;
  int* cnt1    = wsi + OFF_CNT1;
  int2* edge0  = (int2*)(wsi + OFF_EDGE0);
  int2* edge1  = (int2*)(wsi + OFF_EDGE1);
  float* h1    = wsf + OFF_H1;
  _Float16* w1t = (_Float16*)(wsi + OFF_W1T);
  _Float16* g   = (_Float16*)(wsi + OFF_G);

  k_zero<<<128, 256, 0, stream>>>((int4*)d_ws, ZERO_WORDS / 4);
  k_prep<<<32, 256, 0, stream>>>(W1, w1t);
  k_build<<<1024, 256, 0, stream>>>(src0, dst0, ew0, outdeg0, cnt0, edge0,
                                    src1, dst1, ew1, outdeg1, cnt1, edge1);
  k_gemm1<<<2048, 256, 0, stream>>>(x, outdeg0, w1t, g);
  k_gather1<<<(ND0 / 2 + 3) / 4, 256, 0, stream>>>(g, cnt0, edge0, outdeg1, b1, h1);
  k_layer2<<<ND1 / 8, 256, 0, stream>>>(h1, cnt1, edge1, W2, b2, out);
}

// Round 10
// 326.176 us; speedup vs baseline: 1.0088x; 1.0088x over previous
//
#include <hip/hip_runtime.h>

// Problem sizes (match reference)
#define NS0 300000
#define ND0 50000
#define NE0 800000
#define NS1 50000
#define ND1 8192
#define NE1 131072
#define IN_F 256
#define HID_F 128
#define SLOTS 64   // bucket-CSR capacity; indeg ~ Poisson(16), P(>=64) ~ 1e-19
#define NTILE (NS0 / 16)  // 18750 row-tiles for the dense GEMM

typedef __attribute__((ext_vector_type(8))) _Float16 half8_t;
typedef __attribute__((ext_vector_type(4))) float f32x4;

// Workspace layout (4-byte words), all 16B-aligned:
//   outdeg0i [NS0]            @ 0
//   outdeg1i [NS1]            @ 300000
//   cnt0     [ND0]            @ 350000
//   cnt1     [ND1]            @ 400000     -- zeroed range ends 408192 (1.63 MB)
//   edge0    [ND0*SLOTS*2]    @ 408192     ends 6808192   (int2 (src, ew-bits))
//   edge1    [ND1*SLOTS*2]    @ 6808192    ends 7856768
//   h1       [ND0*HID_F f32]  @ 7856768    ends 14256768  (pre-scaled by rsqrt(outdeg1))
//   w1t      [128*256 fp16]   @ 14256768   ends 14273152  (W1 transposed, fp16)
//   g        [NS0*128 fp16]   @ 14273152   ends 33473152  (134 MB total)
#define OFF_OUTDEG0I 0
#define OFF_OUTDEG1I 300000
#define OFF_CNT0     350000
#define OFF_CNT1     400000
#define ZERO_WORDS   408192
#define OFF_EDGE0    408192
#define OFF_EDGE1    6808192
#define OFF_H1       7856768
#define OFF_W1T      14256768
#define OFF_G        14273152

// ----------------------------------------------------------- zero counters
__global__ __launch_bounds__(256) void k_zero(int4* __restrict__ p, int n4) {
  int i = blockIdx.x * 256 + threadIdx.x;
  int s = gridDim.x * 256;
  for (; i < n4; i += s) p[i] = make_int4(0, 0, 0, 0);
}

// ------------------------- W1 [256][128] f32 -> w1t [128][256] f16 (tiny)
__global__ __launch_bounds__(256) void k_prep(
    const float* __restrict__ W1, _Float16* __restrict__ w1t) {
  int i = blockIdx.x * 256 + threadIdx.x;
  int s = gridDim.x * 256;
  for (; i < IN_F * HID_F; i += s) {
    int k = i >> 7, n = i & 127;
    w1t[n * 256 + k] = (_Float16)W1[i];
  }
}

// ------------------- fused degree-histogram + bucket scatter (single pass)
__global__ __launch_bounds__(256) void k_build(
    const int* __restrict__ src0, const int* __restrict__ dst0,
    const float* __restrict__ ew0, int* __restrict__ outdeg0,
    int* __restrict__ cnt0, int2* __restrict__ edge0,
    const int* __restrict__ src1, const int* __restrict__ dst1,
    const float* __restrict__ ew1, int* __restrict__ outdeg1,
    int* __restrict__ cnt1, int2* __restrict__ edge1) {
  int tid = blockIdx.x * blockDim.x + threadIdx.x;
  int stride = gridDim.x * blockDim.x;
  for (int i = tid; i < NE0; i += stride) {
    int s = src0[i];
    int d = dst0[i];
    float w = ew0[i];
    atomicAdd(&outdeg0[s], 1);
    int slot = atomicAdd(&cnt0[d], 1);
    if (slot < SLOTS) edge0[d * SLOTS + slot] = make_int2(s, __float_as_int(w));
  }
  for (int i = tid; i < NE1; i += stride) {
    int s = src1[i];
    int d = dst1[i];
    float w = ew1[i];
    atomicAdd(&outdeg1[s], 1);
    int slot = atomicAdd(&cnt1[d], 1);
    if (slot < SLOTS) edge1[d * SLOTS + slot] = make_int2(s, __float_as_int(w));
  }
}

// ---------------- dense GEMM: g = (x * rsqrt(outdeg0)) @ W1, fp16 in/out,
// fp32 MFMA accumulate. Block = 4 waves; wave wv owns cols [32wv, 32wv+32);
// block processes 16 rows/tile, grid-strides over 18750 tiles.
// B fragments live in 16 NAMED registers (the round-9 bfrag[2][8] array was
// demoted to scratch: VGPR_Count=56 < 64 needed -> 5x slowdown).
#define LDB(p, o) (*reinterpret_cast<const half8_t*>((p) + (o)))
__global__ __launch_bounds__(256, 1) void k_gemm1(
    const float* __restrict__ x, const int* __restrict__ outdeg0,
    const _Float16* __restrict__ w1t, _Float16* __restrict__ g) {
  __shared__ _Float16 outT[16 * 128];
  const int wv = threadIdx.x >> 6;
  const int lane = threadIdx.x & 63;
  const int m = lane & 15;
  const int grp = lane >> 4;

  // A-frag: lane holds x[row=l&15][k = kb*32 + (l>>4)*8 + j] (cvt in-reg)
  // B-frag: lane holds W1[k (same map)][n = 32wv + 16c + (l&15)]
  const _Float16* wb0 = w1t + (size_t)(32 * wv + m) * 256 + grp * 8;
  const _Float16* wb1 = wb0 + 16 * 256;
  const half8_t b00 = LDB(wb0, 0),   b01 = LDB(wb0, 32),  b02 = LDB(wb0, 64),
                b03 = LDB(wb0, 96),  b04 = LDB(wb0, 128), b05 = LDB(wb0, 160),
                b06 = LDB(wb0, 192), b07 = LDB(wb0, 224);
  const half8_t b10 = LDB(wb1, 0),   b11 = LDB(wb1, 32),  b12 = LDB(wb1, 64),
                b13 = LDB(wb1, 96),  b14 = LDB(wb1, 128), b15 = LDB(wb1, 160),
                b16 = LDB(wb1, 192), b17 = LDB(wb1, 224);

  for (int tile = blockIdx.x; tile < NTILE; tile += gridDim.x) {
    const int row = tile * 16 + m;
    const float sc = rsqrtf(fmaxf((float)outdeg0[row], 1.0f));
    f32x4 acc0 = {0.f, 0.f, 0.f, 0.f};
    f32x4 acc1 = {0.f, 0.f, 0.f, 0.f};
    const float* xr = x + (size_t)row * IN_F + grp * 8;
#define STEP(KB, B0, B1)                                                     \
  {                                                                          \
    const float4 xa = *reinterpret_cast<const float4*>(xr + KB * 32);        \
    const float4 xb = *reinterpret_cast<const float4*>(xr + KB * 32 + 4);    \
    half8_t af;                                                              \
    af[0] = (_Float16)(xa.x * sc); af[1] = (_Float16)(xa.y * sc);            \
    af[2] = (_Float16)(xa.z * sc); af[3] = (_Float16)(xa.w * sc);            \
    af[4] = (_Float16)(xb.x * sc); af[5] = (_Float16)(xb.y * sc);            \
    af[6] = (_Float16)(xb.z * sc); af[7] = (_Float16)(xb.w * sc);            \
    acc0 = __builtin_amdgcn_mfma_f32_16x16x32_f16(af, B0, acc0, 0, 0, 0);    \
    acc1 = __builtin_amdgcn_mfma_f32_16x16x32_f16(af, B1, acc1, 0, 0, 0);    \
  }
    STEP(0, b00, b10)
    STEP(1, b01, b11)
    STEP(2, b02, b12)
    STEP(3, b03, b13)
    STEP(4, b04, b14)
    STEP(5, b05, b15)
    STEP(6, b06, b16)
    STEP(7, b07, b17)
#undef STEP
    // C/D layout: col = lane&15, row = 4*(lane>>4) + reg
#pragma unroll
    for (int r = 0; r < 4; ++r) {
      outT[(4 * grp + r) * 128 + 32 * wv + m]      = (_Float16)acc0[r];
      outT[(4 * grp + r) * 128 + 32 * wv + 16 + m] = (_Float16)acc1[r];
    }
    __syncthreads();
    const int r2 = threadIdx.x >> 4;
    const int c2 = threadIdx.x & 15;
    *reinterpret_cast<half8_t*>(g + (size_t)(tile * 16 + r2) * 128 + c2 * 8) =
        *reinterpret_cast<const half8_t*>(outT + r2 * 128 + c2 * 8);
    __syncthreads();
  }
}

// ---------------- layer-1 aggregation over g (fp16, 77 MB, L3-resident):
// h1[d] = relu(rsqrt(indeg)*sum ew*g[src] + b1) * rsqrt(outdeg1[d])
// Wave per dst row; lane (gp=l>>4, sl=l&15): group gp handles edge e+gp,
// 16 lanes x 16B cover the full 256B g-row -> full-line coalesced loads.
// Cross-group reduce: 2 shfl_xor rounds.
__global__ __launch_bounds__(256) void k_gather1(
    const _Float16* __restrict__ g, const int* __restrict__ cnt,
    const int2* __restrict__ edge, const int* __restrict__ outdeg1,
    const float* __restrict__ b1, float* __restrict__ h1) {
  const int w = (blockIdx.x * 256 + threadIdx.x) >> 6;  // dst row
  const int lane = threadIdx.x & 63;
  const int gp = lane >> 4;
  const int sl = lane & 15;
  if (w >= ND0) return;
  const int deg = min(cnt[w], SLOTS);
  const int2* ep = edge + (size_t)w * SLOTS;
  float acc[8] = {0.f, 0.f, 0.f, 0.f, 0.f, 0.f, 0.f, 0.f};
  for (int e = 0; e < deg; e += 4) {
    const int idx = e + gp;
    int2 p = make_int2(0, 0);
    if (idx < deg) p = ep[idx];
    const float c = __int_as_float(p.y);
    const half8_t v =
        *reinterpret_cast<const half8_t*>(g + (size_t)p.x * 128 + sl * 8);
#pragma unroll
    for (int j = 0; j < 8; ++j) acc[j] = fmaf(c, (float)v[j], acc[j]);
  }
#pragma unroll
  for (int j = 0; j < 8; ++j) {
    acc[j] += __shfl_xor(acc[j], 16, 64);
    acc[j] += __shfl_xor(acc[j], 32, 64);
  }
  if (gp == 0) {
    const float sc = rsqrtf(fmaxf((float)deg, 1.0f));
    const float s1 = rsqrtf(fmaxf((float)outdeg1[w], 1.0f));
    const float4 bv0 = *reinterpret_cast<const float4*>(b1 + sl * 8);
    const float4 bv1 = *reinterpret_cast<const float4*>(b1 + sl * 8 + 4);
    float4 o0, o1;
    o0.x = fmaxf(fmaf(acc[0], sc, bv0.x), 0.0f) * s1;
    o0.y = fmaxf(fmaf(acc[1], sc, bv0.y), 0.0f) * s1;
    o0.z = fmaxf(fmaf(acc[2], sc, bv0.z), 0.0f) * s1;
    o0.w = fmaxf(fmaf(acc[3], sc, bv0.w), 0.0f) * s1;
    o1.x = fmaxf(fmaf(acc[4], sc, bv1.x), 0.0f) * s1;
    o1.y = fmaxf(fmaf(acc[5], sc, bv1.y), 0.0f) * s1;
    o1.z = fmaxf(fmaf(acc[6], sc, bv1.z), 0.0f) * s1;
    o1.w = fmaxf(fmaf(acc[7], sc, bv1.w), 0.0f) * s1;
    float* hr = h1 + (size_t)w * 128 + sl * 8;
    *reinterpret_cast<float4*>(hr) = o0;
    *reinterpret_cast<float4*>(hr + 4) = o1;
  }
}

#define FMA2(acc, c, v)        \
  acc.x = fmaf(c, v.x, acc.x); \
  acc.y = fmaf(c, v.y, acc.y);

// --------------------------------------------- fused gather + GEMM, layer 2
// h1 already carries rsqrt(outdeg1); coef = ew only. h1 is 25.6MB, L3-resident.
__global__ __launch_bounds__(256) void k_layer2(
    const float* __restrict__ h1, const int* __restrict__ cnt,
    const int2* __restrict__ edge, const float* __restrict__ W2,
    const float* __restrict__ b2, float* __restrict__ out) {
  __shared__ float arow[8][HID_F];
  const int t = blockIdx.x;
  const int wv = threadIdx.x >> 6;
  const int lane = threadIdx.x & 63;

#pragma unroll
  for (int rr = 0; rr < 2; ++rr) {
    const int row = t * 8 + wv * 2 + rr;
    const int deg = min(cnt[row], SLOTS);
    const int2* ep = edge + (size_t)row * SLOTS;
    float2 acc = make_float2(0.f, 0.f);
    int e = 0;
    for (; e + 4 <= deg; e += 4) {
      int4 q0 = *reinterpret_cast<const int4*>(ep + e);
      int4 q1 = *reinterpret_cast<const int4*>(ep + e + 2);
      float2 v0 = *reinterpret_cast<const float2*>(h1 + (size_t)q0.x * HID_F + lane * 2);
      float2 v1 = *reinterpret_cast<const float2*>(h1 + (size_t)q0.z * HID_F + lane * 2);
      float2 v2 = *reinterpret_cast<const float2*>(h1 + (size_t)q1.x * HID_F + lane * 2);
      float2 v3 = *reinterpret_cast<const float2*>(h1 + (size_t)q1.z * HID_F + lane * 2);
      FMA2(acc, __int_as_float(q0.y), v0);
      FMA2(acc, __int_as_float(q0.w), v1);
      FMA2(acc, __int_as_float(q1.y), v2);
      FMA2(acc, __int_as_float(q1.w), v3);
    }
    for (; e < deg; ++e) {
      int2 p = ep[e];
      float2 v = *reinterpret_cast<const float2*>(h1 + (size_t)p.x * HID_F + lane * 2);
      FMA2(acc, __int_as_float(p.y), v);
    }
    const float sc = rsqrtf(fmaxf((float)deg, 1.0f));
    *reinterpret_cast<float2*>(&arow[wv * 2 + rr][lane * 2]) =
        make_float2(acc.x * sc, acc.y * sc);
  }
  __syncthreads();

  const int j = threadIdx.x & 127;
  const int rg = threadIdx.x >> 7;
  float a0 = 0.f, a1 = 0.f, a2 = 0.f, a3 = 0.f;
  const float* wj = W2 + j;
#pragma unroll 8
  for (int k = 0; k < HID_F; ++k) {
    const float wvv = wj[(size_t)k * 128];
    a0 = fmaf(arow[rg * 4 + 0][k], wvv, a0);
    a1 = fmaf(arow[rg * 4 + 1][k], wvv, a1);
    a2 = fmaf(arow[rg * 4 + 2][k], wvv, a2);
    a3 = fmaf(arow[rg * 4 + 3][k], wvv, a3);
  }
  const float bj = b2[j];
  const int row0 = t * 8 + rg * 4;
  out[(size_t)(row0 + 0) * 128 + j] = fmaxf(a0 + bj, 0.0f);
  out[(size_t)(row0 + 1) * 128 + j] = fmaxf(a1 + bj, 0.0f);
  out[(size_t)(row0 + 2) * 128 + j] = fmaxf(a2 + bj, 0.0f);
  out[(size_t)(row0 + 3) * 128 + j] = fmaxf(a3 + bj, 0.0f);
}

extern "C" void kernel_launch(void* const* d_in, const int* in_sizes, int n_in,
                              void* d_out, int out_size, void* d_ws, size_t ws_size,
                              hipStream_t stream) {
  const float* x    = (const float*)d_in[0];
  const int*   src0 = (const int*)d_in[1];
  const int*   dst0 = (const int*)d_in[2];
  const float* ew0  = (const float*)d_in[3];
  const int*   src1 = (const int*)d_in[4];
  const int*   dst1 = (const int*)d_in[5];
  const float* ew1  = (const float*)d_in[6];
  const float* W1   = (const float*)d_in[7];
  const float* b1   = (const float*)d_in[8];
  const float* W2   = (const float*)d_in[9];
  const float* b2   = (const float*)d_in[10];
  float* out = (float*)d_out;

  int*   wsi = (int*)d_ws;
  float* wsf = (float*)d_ws;
  int* outdeg0 = wsi + OFF_OUTDEG0I;
  int* outdeg1 = wsi + OFF_OUTDEG1I;
  int* cnt0    = wsi + OFF_CNT0;
  int* cnt1    = wsi + OFF_CNT1;
  int2* edge0  = (int2*)(wsi + OFF_EDGE0);
  int2* edge1  = (int2*)(wsi + OFF_EDGE1);
  float* h1    = wsf + OFF_H1;
  _Float16* w1t = (_Float16*)(wsi + OFF_W1T);
  _Float16* g   = (_Float16*)(wsi + OFF_G);

  k_zero<<<128, 256, 0, stream>>>((int4*)d_ws, ZERO_WORDS / 4);
  k_prep<<<32, 256, 0, stream>>>(W1, w1t);
  k_build<<<1024, 256, 0, stream>>>(src0, dst0, ew0, outdeg0, cnt0, edge0,
                                    src1, dst1, ew1, outdeg1, cnt1, edge1);
  k_gemm1<<<2048, 256, 0, stream>>>(x, outdeg0, w1t, g);
  k_gather1<<<(ND0 * 64) / 256, 256, 0, stream>>>(g, cnt0, edge0, outdeg1, b1, h1);
  k_layer2<<<ND1 / 8, 256, 0, stream>>>(h1, cnt1, edge1, W2, b2, out);
}

// Round 11
// 324.502 us; speedup vs baseline: 1.0140x; 1.0052x over previous
//
#include <hip/hip_runtime.h>

// Problem sizes (match reference)
#define NS0 300000
#define ND0 50000
#define NE0 800000
#define NS1 50000
#define ND1 8192
#define NE1 131072
#define IN_F 256
#define HID_F 128
#define SLOTS 64   // bucket-CSR capacity; indeg ~ Poisson(16), P(>=64) ~ 1e-19
#define NTILE (NS0 / 16)  // 18750 row-tiles for the dense GEMM

typedef __attribute__((ext_vector_type(8))) _Float16 half8_t;
typedef __attribute__((ext_vector_type(4))) float f32x4;

// Workspace layout (4-byte words), all 16B-aligned:
//   outdeg0i [NS0]            @ 0
//   outdeg1i [NS1]            @ 300000
//   cnt0     [ND0]            @ 350000
//   cnt1     [ND1]            @ 400000     -- zeroed range ends 408192 (1.63 MB)
//   edge0    [ND0*SLOTS*2]    @ 408192     ends 6808192   (int2 (src, ew-bits))
//   edge1    [ND1*SLOTS*2]    @ 6808192    ends 7856768
//   h1       [ND0*HID_F f32]  @ 7856768    ends 14256768  (pre-scaled by rsqrt(outdeg1))
//   w1t      [128*256 fp16]   @ 14256768   ends 14273152  (W1 transposed, fp16)
//   g        [NS0*128 fp16]   @ 14273152   ends 33473152  (134 MB total)
#define OFF_OUTDEG0I 0
#define OFF_OUTDEG1I 300000
#define OFF_CNT0     350000
#define OFF_CNT1     400000
#define ZERO_WORDS   408192
#define OFF_EDGE0    408192
#define OFF_EDGE1    6808192
#define OFF_H1       7856768
#define OFF_W1T      14256768
#define OFF_G        14273152

// ----------------------------------------------------------- zero counters
__global__ __launch_bounds__(256) void k_zero(int4* __restrict__ p, int n4) {
  int i = blockIdx.x * 256 + threadIdx.x;
  int s = gridDim.x * 256;
  for (; i < n4; i += s) p[i] = make_int4(0, 0, 0, 0);
}

// ------------------------- W1 [256][128] f32 -> w1t [128][256] f16 (tiny)
__global__ __launch_bounds__(256) void k_prep(
    const float* __restrict__ W1, _Float16* __restrict__ w1t) {
  int i = blockIdx.x * 256 + threadIdx.x;
  int s = gridDim.x * 256;
  for (; i < IN_F * HID_F; i += s) {
    int k = i >> 7, n = i & 127;
    w1t[n * 256 + k] = (_Float16)W1[i];
  }
}

// ------------------- fused degree-histogram + bucket scatter (single pass)
__global__ __launch_bounds__(256) void k_build(
    const int* __restrict__ src0, const int* __restrict__ dst0,
    const float* __restrict__ ew0, int* __restrict__ outdeg0,
    int* __restrict__ cnt0, int2* __restrict__ edge0,
    const int* __restrict__ src1, const int* __restrict__ dst1,
    const float* __restrict__ ew1, int* __restrict__ outdeg1,
    int* __restrict__ cnt1, int2* __restrict__ edge1) {
  int tid = blockIdx.x * blockDim.x + threadIdx.x;
  int stride = gridDim.x * blockDim.x;
  for (int i = tid; i < NE0; i += stride) {
    int s = src0[i];
    int d = dst0[i];
    float w = ew0[i];
    atomicAdd(&outdeg0[s], 1);
    int slot = atomicAdd(&cnt0[d], 1);
    if (slot < SLOTS) edge0[d * SLOTS + slot] = make_int2(s, __float_as_int(w));
  }
  for (int i = tid; i < NE1; i += stride) {
    int s = src1[i];
    int d = dst1[i];
    float w = ew1[i];
    atomicAdd(&outdeg1[s], 1);
    int slot = atomicAdd(&cnt1[d], 1);
    if (slot < SLOTS) edge1[d * SLOTS + slot] = make_int2(s, __float_as_int(w));
  }
}

// ---------------- dense GEMM: g = (x * rsqrt(outdeg0)) @ W1, fp16 in/out,
// fp32 MFMA accumulate. Block = 4 waves; wave wv owns cols [32wv, 32wv+32);
// 16 rows/tile, grid-stride over 18750 tiles. BARRIER-FREE: the D-fragment ->
// row-major transpose uses a WAVE-PRIVATE LDS patch (within-wave exchange
// only, ordered by lgkmcnt), so tiles pipeline with no __syncthreads drains
// (round-10 post-mortem: 2 barriers/tile each forcing vmcnt(0) was the stall).
#define LDB(p, o) (*reinterpret_cast<const half8_t*>((p) + (o)))
__global__ __launch_bounds__(256) void k_gemm1(
    const float* __restrict__ x, const int* __restrict__ outdeg0,
    const _Float16* __restrict__ w1t, _Float16* __restrict__ g) {
  // wave-private transpose patch: 16 rows x 32 cols, row stride 40 halves
  // (80B: 16B-aligned for b128 reads; 20-word stride spreads banks)
  __shared__ _Float16 ldsT[4][16 * 40];
  const int wv = threadIdx.x >> 6;
  const int lane = threadIdx.x & 63;
  const int m = lane & 15;
  const int grp = lane >> 4;
  _Float16* tp = ldsT[wv];

  // A-frag: lane holds x[row=tile*16 + (l&15)][k = kb*32 + (l>>4)*8 + j]
  // B-frag: lane holds W1[k (same map)][n = 32wv + 16c + (l&15)]
  const _Float16* wb0 = w1t + (size_t)(32 * wv + m) * 256 + grp * 8;
  const _Float16* wb1 = wb0 + 16 * 256;
  const half8_t b00 = LDB(wb0, 0),   b01 = LDB(wb0, 32),  b02 = LDB(wb0, 64),
                b03 = LDB(wb0, 96),  b04 = LDB(wb0, 128), b05 = LDB(wb0, 160),
                b06 = LDB(wb0, 192), b07 = LDB(wb0, 224);
  const half8_t b10 = LDB(wb1, 0),   b11 = LDB(wb1, 32),  b12 = LDB(wb1, 64),
                b13 = LDB(wb1, 96),  b14 = LDB(wb1, 128), b15 = LDB(wb1, 160),
                b16 = LDB(wb1, 192), b17 = LDB(wb1, 224);

  const int row_r = lane >> 2;   // store phase: row 0..15
  const int q_r   = lane & 3;    // store phase: 8-col quarter

  for (int tile = blockIdx.x; tile < NTILE; tile += gridDim.x) {
    const int row = tile * 16 + m;
    const float sc = rsqrtf(fmaxf((float)outdeg0[row], 1.0f));
    f32x4 acc0 = {0.f, 0.f, 0.f, 0.f};
    f32x4 acc1 = {0.f, 0.f, 0.f, 0.f};
    const float* xr = x + (size_t)row * IN_F + grp * 8;
#define STEP(KB, B0, B1)                                                     \
  {                                                                          \
    const float4 xa = *reinterpret_cast<const float4*>(xr + KB * 32);        \
    const float4 xb = *reinterpret_cast<const float4*>(xr + KB * 32 + 4);    \
    half8_t af;                                                              \
    af[0] = (_Float16)(xa.x * sc); af[1] = (_Float16)(xa.y * sc);            \
    af[2] = (_Float16)(xa.z * sc); af[3] = (_Float16)(xa.w * sc);            \
    af[4] = (_Float16)(xb.x * sc); af[5] = (_Float16)(xb.y * sc);            \
    af[6] = (_Float16)(xb.z * sc); af[7] = (_Float16)(xb.w * sc);            \
    acc0 = __builtin_amdgcn_mfma_f32_16x16x32_f16(af, B0, acc0, 0, 0, 0);    \
    acc1 = __builtin_amdgcn_mfma_f32_16x16x32_f16(af, B1, acc1, 0, 0, 0);    \
  }
    STEP(0, b00, b10)
    STEP(1, b01, b11)
    STEP(2, b02, b12)
    STEP(3, b03, b13)
    STEP(4, b04, b14)
    STEP(5, b05, b15)
    STEP(6, b06, b16)
    STEP(7, b07, b17)
#undef STEP
    // D layout: col-within-wave = (16c + (lane&15)), out-row = 4*(lane>>4)+r.
    // Scatter D into the wave-private patch as row-major [16][32]:
#pragma unroll
    for (int r = 0; r < 4; ++r) {
      tp[(4 * grp + r) * 40 + m]      = (_Float16)acc0[r];
      tp[(4 * grp + r) * 40 + 16 + m] = (_Float16)acc1[r];
    }
    // Coalesced store: lane (row_r, q_r) emits 16B of row-major g.
    const half8_t ov = *reinterpret_cast<const half8_t*>(tp + row_r * 40 + q_r * 8);
    *reinterpret_cast<half8_t*>(
        g + (size_t)(tile * 16 + row_r) * 128 + 32 * wv + q_r * 8) = ov;
  }
}

// ---------------- layer-1 aggregation over g (fp16, 77 MB, L3-resident):
// h1[d] = relu(rsqrt(indeg)*sum ew*g[src] + b1) * rsqrt(outdeg1[d])
// Wave per dst row; lane (gp=l>>4, sl=l&15): group gp handles edge e+gp,
// 16 lanes x 16B cover the full 256B g-row -> full-line coalesced loads.
__global__ __launch_bounds__(256) void k_gather1(
    const _Float16* __restrict__ g, const int* __restrict__ cnt,
    const int2* __restrict__ edge, const int* __restrict__ outdeg1,
    const float* __restrict__ b1, float* __restrict__ h1) {
  const int w = (blockIdx.x * 256 + threadIdx.x) >> 6;  // dst row
  const int lane = threadIdx.x & 63;
  const int gp = lane >> 4;
  const int sl = lane & 15;
  if (w >= ND0) return;
  const int deg = min(cnt[w], SLOTS);
  const int2* ep = edge + (size_t)w * SLOTS;
  float acc[8] = {0.f, 0.f, 0.f, 0.f, 0.f, 0.f, 0.f, 0.f};
  for (int e = 0; e < deg; e += 4) {
    const int idx = e + gp;
    int2 p = make_int2(0, 0);
    if (idx < deg) p = ep[idx];
    const float c = __int_as_float(p.y);
    const half8_t v =
        *reinterpret_cast<const half8_t*>(g + (size_t)p.x * 128 + sl * 8);
#pragma unroll
    for (int j = 0; j < 8; ++j) acc[j] = fmaf(c, (float)v[j], acc[j]);
  }
#pragma unroll
  for (int j = 0; j < 8; ++j) {
    acc[j] += __shfl_xor(acc[j], 16, 64);
    acc[j] += __shfl_xor(acc[j], 32, 64);
  }
  if (gp == 0) {
    const float sc = rsqrtf(fmaxf((float)deg, 1.0f));
    const float s1 = rsqrtf(fmaxf((float)outdeg1[w], 1.0f));
    const float4 bv0 = *reinterpret_cast<const float4*>(b1 + sl * 8);
    const float4 bv1 = *reinterpret_cast<const float4*>(b1 + sl * 8 + 4);
    float4 o0, o1;
    o0.x = fmaxf(fmaf(acc[0], sc, bv0.x), 0.0f) * s1;
    o0.y = fmaxf(fmaf(acc[1], sc, bv0.y), 0.0f) * s1;
    o0.z = fmaxf(fmaf(acc[2], sc, bv0.z), 0.0f) * s1;
    o0.w = fmaxf(fmaf(acc[3], sc, bv0.w), 0.0f) * s1;
    o1.x = fmaxf(fmaf(acc[4], sc, bv1.x), 0.0f) * s1;
    o1.y = fmaxf(fmaf(acc[5], sc, bv1.y), 0.0f) * s1;
    o1.z = fmaxf(fmaf(acc[6], sc, bv1.z), 0.0f) * s1;
    o1.w = fmaxf(fmaf(acc[7], sc, bv1.w), 0.0f) * s1;
    float* hr = h1 + (size_t)w * 128 + sl * 8;
    *reinterpret_cast<float4*>(hr) = o0;
    *reinterpret_cast<float4*>(hr + 4) = o1;
  }
}

#define FMA2(acc, c, v)        \
  acc.x = fmaf(c, v.x, acc.x); \
  acc.y = fmaf(c, v.y, acc.y);

// --------------------------------------------- fused gather + GEMM, layer 2
// h1 already carries rsqrt(outdeg1); coef = ew only. h1 is 25.6MB, L3-resident.
__global__ __launch_bounds__(256) void k_layer2(
    const float* __restrict__ h1, const int* __restrict__ cnt,
    const int2* __restrict__ edge, const float* __restrict__ W2,
    const float* __restrict__ b2, float* __restrict__ out) {
  __shared__ float arow[8][HID_F];
  const int t = blockIdx.x;
  const int wv = threadIdx.x >> 6;
  const int lane = threadIdx.x & 63;

#pragma unroll
  for (int rr = 0; rr < 2; ++rr) {
    const int row = t * 8 + wv * 2 + rr;
    const int deg = min(cnt[row], SLOTS);
    const int2* ep = edge + (size_t)row * SLOTS;
    float2 acc = make_float2(0.f, 0.f);
    int e = 0;
    for (; e + 4 <= deg; e += 4) {
      int4 q0 = *reinterpret_cast<const int4*>(ep + e);
      int4 q1 = *reinterpret_cast<const int4*>(ep + e + 2);
      float2 v0 = *reinterpret_cast<const float2*>(h1 + (size_t)q0.x * HID_F + lane * 2);
      float2 v1 = *reinterpret_cast<const float2*>(h1 + (size_t)q0.z * HID_F + lane * 2);
      float2 v2 = *reinterpret_cast<const float2*>(h1 + (size_t)q1.x * HID_F + lane * 2);
      float2 v3 = *reinterpret_cast<const float2*>(h1 + (size_t)q1.z * HID_F + lane * 2);
      FMA2(acc, __int_as_float(q0.y), v0);
      FMA2(acc, __int_as_float(q0.w), v1);
      FMA2(acc, __int_as_float(q1.y), v2);
      FMA2(acc, __int_as_float(q1.w), v3);
    }
    for (; e < deg; ++e) {
      int2 p = ep[e];
      float2 v = *reinterpret_cast<const float2*>(h1 + (size_t)p.x * HID_F + lane * 2);
      FMA2(acc, __int_as_float(p.y), v);
    }
    const float sc = rsqrtf(fmaxf((float)deg, 1.0f));
    *reinterpret_cast<float2*>(&arow[wv * 2 + rr][lane * 2]) =
        make_float2(acc.x * sc, acc.y * sc);
  }
  __syncthreads();

  const int j = threadIdx.x & 127;
  const int rg = threadIdx.x >> 7;
  float a0 = 0.f, a1 = 0.f, a2 = 0.f, a3 = 0.f;
  const float* wj = W2 + j;
#pragma unroll 8
  for (int k = 0; k < HID_F; ++k) {
    const float wvv = wj[(size_t)k * 128];
    a0 = fmaf(arow[rg * 4 + 0][k], wvv, a0);
    a1 = fmaf(arow[rg * 4 + 1][k], wvv, a1);
    a2 = fmaf(arow[rg * 4 + 2][k], wvv, a2);
    a3 = fmaf(arow[rg * 4 + 3][k], wvv, a3);
  }
  const float bj = b2[j];
  const int row0 = t * 8 + rg * 4;
  out[(size_t)(row0 + 0) * 128 + j] = fmaxf(a0 + bj, 0.0f);
  out[(size_t)(row0 + 1) * 128 + j] = fmaxf(a1 + bj, 0.0f);
  out[(size_t)(row0 + 2) * 128 + j] = fmaxf(a2 + bj, 0.0f);
  out[(size_t)(row0 + 3) * 128 + j] = fmaxf(a3 + bj, 0.0f);
}

extern "C" void kernel_launch(void* const* d_in, const int* in_sizes, int n_in,
                              void* d_out, int out_size, void* d_ws, size_t ws_size,
                              hipStream_t stream) {
  const float* x    = (const float*)d_in[0];
  const int*   src0 = (const int*)d_in[1];
  const int*   dst0 = (const int*)d_in[2];
  const float* ew0  = (const float*)d_in[3];
  const int*   src1 = (const int*)d_in[4];
  const int*   dst1 = (const int*)d_in[5];
  const float* ew1  = (const float*)d_in[6];
  const float* W1   = (const float*)d_in[7];
  const float* b1   = (const float*)d_in[8];
  const float* W2   = (const float*)d_in[9];
  const float* b2   = (const float*)d_in[10];
  float* out = (float*)d_out;

  int*   wsi = (int*)d_ws;
  float* wsf = (float*)d_ws;
  int* outdeg0 = wsi + OFF_OUTDEG0I;
  int* outdeg1 = wsi + OFF_OUTDEG1I;
  int* cnt0    = wsi + OFF_CNT0;
  int* cnt1    = wsi + OFF_CNT1;
  int2* edge0  = (int2*)(wsi + OFF_EDGE0);
  int2* edge1  = (int2*)(wsi + OFF_EDGE1);
  float* h1    = wsf + OFF_H1;
  _Float16* w1t = (_Float16*)(wsi + OFF_W1T);
  _Float16* g   = (_Float16*)(wsi + OFF_G);

  k_zero<<<128, 256, 0, stream>>>((int4*)d_ws, ZERO_WORDS / 4);
  k_prep<<<32, 256, 0, stream>>>(W1, w1t);
  k_build<<<1024, 256, 0, stream>>>(src0, dst0, ew0, outdeg0, cnt0, edge0,
                                    src1, dst1, ew1, outdeg1, cnt1, edge1);
  k_gemm1<<<2048, 256, 0, stream>>>(x, outdeg0, w1t, g);
  k_gather1<<<(ND0 * 64) / 256, 256, 0, stream>>>(g, cnt0, edge0, outdeg1, b1, h1);
  k_layer2<<<ND1 / 8, 256, 0, stream>>>(h1, cnt1, edge1, W2, b2, out);
}

// Round 12
// 240.302 us; speedup vs baseline: 1.3693x; 1.3504x over previous
//
#include <hip/hip_runtime.h>

// Problem sizes (match reference)
#define NS0 300000
#define ND0 50000
#define NE0 800000
#define NS1 50000
#define ND1 8192
#define NE1 131072
#define IN_F 256
#define HID_F 128
#define SLOTS 64   // bucket-CSR capacity; indeg ~ Poisson(16), P(>=64) ~ 1e-19
#define NTILE (NS0 / 16)  // 18750 row-tiles for the dense GEMM
#define GEMM_GRID 2048

typedef __attribute__((ext_vector_type(8))) _Float16 half8_t;
typedef __attribute__((ext_vector_type(4))) _Float16 half4_t;
typedef __attribute__((ext_vector_type(4))) float f32x4;

// Workspace layout (4-byte words), all 16B-aligned:
#define OFF_OUTDEG0I 0
#define OFF_OUTDEG1I 300000
#define OFF_CNT0     350000
#define OFF_CNT1     400000
#define ZERO_WORDS   408192
#define OFF_EDGE0    408192
#define OFF_EDGE1    6808192
#define OFF_H1       7856768
#define OFF_W1T      14256768
#define OFF_G        14273152

// ----------------------------------------------------------- zero counters
__global__ __launch_bounds__(256) void k_zero(int4* __restrict__ p, int n4) {
  int i = blockIdx.x * 256 + threadIdx.x;
  int s = gridDim.x * 256;
  for (; i < n4; i += s) p[i] = make_int4(0, 0, 0, 0);
}

// ------------------------- W1 [256][128] f32 -> w1t [128][256] f16 (tiny)
__global__ __launch_bounds__(256) void k_prep(
    const float* __restrict__ W1, _Float16* __restrict__ w1t) {
  int i = blockIdx.x * 256 + threadIdx.x;
  int s = gridDim.x * 256;
  for (; i < IN_F * HID_F; i += s) {
    int k = i >> 7, n = i & 127;
    w1t[n * 256 + k] = (_Float16)W1[i];
  }
}

// ------------------- fused degree-histogram + bucket scatter (single pass)
__global__ __launch_bounds__(256) void k_build(
    const int* __restrict__ src0, const int* __restrict__ dst0,
    const float* __restrict__ ew0, int* __restrict__ outdeg0,
    int* __restrict__ cnt0, int2* __restrict__ edge0,
    const int* __restrict__ src1, const int* __restrict__ dst1,
    const float* __restrict__ ew1, int* __restrict__ outdeg1,
    int* __restrict__ cnt1, int2* __restrict__ edge1) {
  int tid = blockIdx.x * blockDim.x + threadIdx.x;
  int stride = gridDim.x * blockDim.x;
  for (int i = tid; i < NE0; i += stride) {
    int s = src0[i];
    int d = dst0[i];
    float w = ew0[i];
    atomicAdd(&outdeg0[s], 1);
    int slot = atomicAdd(&cnt0[d], 1);
    if (slot < SLOTS) edge0[d * SLOTS + slot] = make_int2(s, __float_as_int(w));
  }
  for (int i = tid; i < NE1; i += stride) {
    int s = src1[i];
    int d = dst1[i];
    float w = ew1[i];
    atomicAdd(&outdeg1[s], 1);
    int slot = atomicAdd(&cnt1[d], 1);
    if (slot < SLOTS) edge1[d * SLOTS + slot] = make_int2(s, __float_as_int(w));
  }
}

// ---------------- dense GEMM: g = (x * rsqrt(outdeg0)) @ W1, MFMA fp16.
// v3: A staged through LDS. Round-11 post-mortem: strided A loads (lane l
// reads row l&15, 1KB apart -> 32 lines/instr) were the issue-rate bound;
// dur was identical whether x came from HBM or L3. Now the block loads its
// contiguous 16KB x-chunk DENSELY (1KB/instr/wave), scales+converts to f16,
// and stores to LDS in fragment order with XOR swizzle S = idx^kb^grp
// (conflict-free both sides). Inner loop: ds_read_b128 + 2 MFMA per K-step.
// Double-buffered; next tile's loads issued before compute (latency hidden).
#define LDB(p, o) (*reinterpret_cast<const half8_t*>((p) + (o)))
__global__ __launch_bounds__(256) void k_gemm1(
    const float* __restrict__ x, const int* __restrict__ outdeg0,
    const _Float16* __restrict__ w1t, _Float16* __restrict__ g) {
  __shared__ __align__(16) _Float16 ldsA[2][16 * 256];  // 2 x 8KB, frag-order
  __shared__ _Float16 ldsT[4][16 * 40];                  // epilogue transpose
  const int tid = threadIdx.x;
  const int wv = tid >> 6;
  const int lane = tid & 63;
  const int m = lane & 15;
  const int grp = lane >> 4;
  _Float16* tp = ldsT[wv];

  // B-frag: lane holds W1[k = kb*32 + grp*8 + j][n = 32wv + 16c + m]
  const _Float16* wb0 = w1t + (size_t)(32 * wv + m) * 256 + grp * 8;
  const _Float16* wb1 = wb0 + 16 * 256;
  const half8_t b00 = LDB(wb0, 0),   b01 = LDB(wb0, 32),  b02 = LDB(wb0, 64),
                b03 = LDB(wb0, 96),  b04 = LDB(wb0, 128), b05 = LDB(wb0, 160),
                b06 = LDB(wb0, 192), b07 = LDB(wb0, 224);
  const half8_t b10 = LDB(wb1, 0),   b11 = LDB(wb1, 32),  b12 = LDB(wb1, 64),
                b13 = LDB(wb1, 96),  b14 = LDB(wb1, 128), b15 = LDB(wb1, 160),
                b16 = LDB(wb1, 192), b17 = LDB(wb1, 224);

  // staging constants: lane covers quartet kq = lane of each row-group
  const int skb = lane >> 3;          // K-block 0..7
  const int sgrp = (lane >> 1) & 3;   // k-octet group 0..3
  const int sjh = lane & 1;           // which half of the octet
  // swizzled byte offset inside a buffer for staging row mr:
  //   idx = skb*64 + sgrp*16 + mr ; S = idx ^ skb ^ sgrp ; byte = S*16 + sjh*8
  const int row_r = lane >> 2;        // epilogue: row 0..15
  const int q_r   = lane & 3;         // epilogue: 8-col quarter

  const int bid = blockIdx.x;
  float4 pv[4];
  float psc[4];

  // ---- prologue: stage tile bid into buf 0 (serial, once)
  {
    const float* tb = x + (size_t)bid * 4096;
#pragma unroll
    for (int r = 0; r < 4; ++r) {
      const int mr = wv + 4 * r;
      const float4 v = *reinterpret_cast<const float4*>(tb + tid * 4 + r * 1024);
      const float s = rsqrtf(fmaxf((float)outdeg0[bid * 16 + mr], 1.0f));
      half4_t h;
      h[0] = (_Float16)(v.x * s); h[1] = (_Float16)(v.y * s);
      h[2] = (_Float16)(v.z * s); h[3] = (_Float16)(v.w * s);
      const int idx = skb * 64 + sgrp * 16 + mr;
      const int S = idx ^ skb ^ sgrp;
      *reinterpret_cast<half4_t*>(
          reinterpret_cast<char*>(&ldsA[0][0]) + S * 16 + sjh * 8) = h;
    }
  }
  __syncthreads();

  int cur = 0;
  for (int tile = bid; tile < NTILE; tile += GEMM_GRID) {
    const int nxt = tile + GEMM_GRID;
    // (a) issue next tile's dense loads (latency hides under compute)
    if (nxt < NTILE) {
      const float* tb = x + (size_t)nxt * 4096;
#pragma unroll
      for (int r = 0; r < 4; ++r) {
        pv[r] = *reinterpret_cast<const float4*>(tb + tid * 4 + r * 1024);
        psc[r] = rsqrtf(fmaxf((float)outdeg0[nxt * 16 + wv + 4 * r], 1.0f));
      }
    }
    // (b) compute current tile from LDS
    {
      const char* A = reinterpret_cast<const char*>(&ldsA[cur][0]);
      f32x4 acc0 = {0.f, 0.f, 0.f, 0.f};
      f32x4 acc1 = {0.f, 0.f, 0.f, 0.f};
#define STEP(KB, B0, B1)                                                       \
  {                                                                            \
    const int Sr = ((KB * 64 + lane) ^ KB ^ grp);                              \
    const half8_t af = *reinterpret_cast<const half8_t*>(A + Sr * 16);         \
    acc0 = __builtin_amdgcn_mfma_f32_16x16x32_f16(af, B0, acc0, 0, 0, 0);      \
    acc1 = __builtin_amdgcn_mfma_f32_16x16x32_f16(af, B1, acc1, 0, 0, 0);      \
  }
      STEP(0, b00, b10)
      STEP(1, b01, b11)
      STEP(2, b02, b12)
      STEP(3, b03, b13)
      STEP(4, b04, b14)
      STEP(5, b05, b15)
      STEP(6, b06, b16)
      STEP(7, b07, b17)
#undef STEP
      // epilogue: wave-private transpose patch -> coalesced g store
#pragma unroll
      for (int r = 0; r < 4; ++r) {
        tp[(4 * grp + r) * 40 + m]      = (_Float16)acc0[r];
        tp[(4 * grp + r) * 40 + 16 + m] = (_Float16)acc1[r];
      }
      const half8_t ov =
          *reinterpret_cast<const half8_t*>(tp + row_r * 40 + q_r * 8);
      *reinterpret_cast<half8_t*>(
          g + (size_t)(tile * 16 + row_r) * 128 + 32 * wv + q_r * 8) = ov;
    }
    // (c) convert + write next tile into the other buffer
    if (nxt < NTILE) {
      char* B = reinterpret_cast<char*>(&ldsA[cur ^ 1][0]);
#pragma unroll
      for (int r = 0; r < 4; ++r) {
        const int mr = wv + 4 * r;
        half4_t h;
        h[0] = (_Float16)(pv[r].x * psc[r]); h[1] = (_Float16)(pv[r].y * psc[r]);
        h[2] = (_Float16)(pv[r].z * psc[r]); h[3] = (_Float16)(pv[r].w * psc[r]);
        const int idx = skb * 64 + sgrp * 16 + mr;
        const int S = idx ^ skb ^ sgrp;
        *reinterpret_cast<half4_t*>(B + S * 16 + sjh * 8) = h;
      }
    }
    // (d) one barrier per tile
    __syncthreads();
    cur ^= 1;
  }
}

// ---------------- layer-1 aggregation over g (fp16, 77 MB, L3-resident):
// h1[d] = relu(rsqrt(indeg)*sum ew*g[src] + b1) * rsqrt(outdeg1[d])
__global__ __launch_bounds__(256) void k_gather1(
    const _Float16* __restrict__ g, const int* __restrict__ cnt,
    const int2* __restrict__ edge, const int* __restrict__ outdeg1,
    const float* __restrict__ b1, float* __restrict__ h1) {
  const int w = (blockIdx.x * 256 + threadIdx.x) >> 6;  // dst row
  const int lane = threadIdx.x & 63;
  const int gp = lane >> 4;
  const int sl = lane & 15;
  if (w >= ND0) return;
  const int deg = min(cnt[w], SLOTS);
  const int2* ep = edge + (size_t)w * SLOTS;
  float acc[8] = {0.f, 0.f, 0.f, 0.f, 0.f, 0.f, 0.f, 0.f};
  for (int e = 0; e < deg; e += 4) {
    const int idx = e + gp;
    int2 p = make_int2(0, 0);
    if (idx < deg) p = ep[idx];
    const float c = __int_as_float(p.y);
    const half8_t v =
        *reinterpret_cast<const half8_t*>(g + (size_t)p.x * 128 + sl * 8);
#pragma unroll
    for (int j = 0; j < 8; ++j) acc[j] = fmaf(c, (float)v[j], acc[j]);
  }
#pragma unroll
  for (int j = 0; j < 8; ++j) {
    acc[j] += __shfl_xor(acc[j], 16, 64);
    acc[j] += __shfl_xor(acc[j], 32, 64);
  }
  if (gp == 0) {
    const float sc = rsqrtf(fmaxf((float)deg, 1.0f));
    const float s1 = rsqrtf(fmaxf((float)outdeg1[w], 1.0f));
    const float4 bv0 = *reinterpret_cast<const float4*>(b1 + sl * 8);
    const float4 bv1 = *reinterpret_cast<const float4*>(b1 + sl * 8 + 4);
    float4 o0, o1;
    o0.x = fmaxf(fmaf(acc[0], sc, bv0.x), 0.0f) * s1;
    o0.y = fmaxf(fmaf(acc[1], sc, bv0.y), 0.0f) * s1;
    o0.z = fmaxf(fmaf(acc[2], sc, bv0.z), 0.0f) * s1;
    o0.w = fmaxf(fmaf(acc[3], sc, bv0.w), 0.0f) * s1;
    o1.x = fmaxf(fmaf(acc[4], sc, bv1.x), 0.0f) * s1;
    o1.y = fmaxf(fmaf(acc[5], sc, bv1.y), 0.0f) * s1;
    o1.z = fmaxf(fmaf(acc[6], sc, bv1.z), 0.0f) * s1;
    o1.w = fmaxf(fmaf(acc[7], sc, bv1.w), 0.0f) * s1;
    float* hr = h1 + (size_t)w * 128 + sl * 8;
    *reinterpret_cast<float4*>(hr) = o0;
    *reinterpret_cast<float4*>(hr + 4) = o1;
  }
}

#define FMA2(acc, c, v)        \
  acc.x = fmaf(c, v.x, acc.x); \
  acc.y = fmaf(c, v.y, acc.y);

// --------------------------------------------- fused gather + GEMM, layer 2
__global__ __launch_bounds__(256) void k_layer2(
    const float* __restrict__ h1, const int* __restrict__ cnt,
    const int2* __restrict__ edge, const float* __restrict__ W2,
    const float* __restrict__ b2, float* __restrict__ out) {
  __shared__ float arow[8][HID_F];
  const int t = blockIdx.x;
  const int wv = threadIdx.x >> 6;
  const int lane = threadIdx.x & 63;

#pragma unroll
  for (int rr = 0; rr < 2; ++rr) {
    const int row = t * 8 + wv * 2 + rr;
    const int deg = min(cnt[row], SLOTS);
    const int2* ep = edge + (size_t)row * SLOTS;
    float2 acc = make_float2(0.f, 0.f);
    int e = 0;
    for (; e + 4 <= deg; e += 4) {
      int4 q0 = *reinterpret_cast<const int4*>(ep + e);
      int4 q1 = *reinterpret_cast<const int4*>(ep + e + 2);
      float2 v0 = *reinterpret_cast<const float2*>(h1 + (size_t)q0.x * HID_F + lane * 2);
      float2 v1 = *reinterpret_cast<const float2*>(h1 + (size_t)q0.z * HID_F + lane * 2);
      float2 v2 = *reinterpret_cast<const float2*>(h1 + (size_t)q1.x * HID_F + lane * 2);
      float2 v3 = *reinterpret_cast<const float2*>(h1 + (size_t)q1.z * HID_F + lane * 2);
      FMA2(acc, __int_as_float(q0.y), v0);
      FMA2(acc, __int_as_float(q0.w), v1);
      FMA2(acc, __int_as_float(q1.y), v2);
      FMA2(acc, __int_as_float(q1.w), v3);
    }
    for (; e < deg; ++e) {
      int2 p = ep[e];
      float2 v = *reinterpret_cast<const float2*>(h1 + (size_t)p.x * HID_F + lane * 2);
      FMA2(acc, __int_as_float(p.y), v);
    }
    const float sc = rsqrtf(fmaxf((float)deg, 1.0f));
    *reinterpret_cast<float2*>(&arow[wv * 2 + rr][lane * 2]) =
        make_float2(acc.x * sc, acc.y * sc);
  }
  __syncthreads();

  const int j = threadIdx.x & 127;
  const int rg = threadIdx.x >> 7;
  float a0 = 0.f, a1 = 0.f, a2 = 0.f, a3 = 0.f;
  const float* wj = W2 + j;
#pragma unroll 8
  for (int k = 0; k < HID_F; ++k) {
    const float wvv = wj[(size_t)k * 128];
    a0 = fmaf(arow[rg * 4 + 0][k], wvv, a0);
    a1 = fmaf(arow[rg * 4 + 1][k], wvv, a1);
    a2 = fmaf(arow[rg * 4 + 2][k], wvv, a2);
    a3 = fmaf(arow[rg * 4 + 3][k], wvv, a3);
  }
  const float bj = b2[j];
  const int row0 = t * 8 + rg * 4;
  out[(size_t)(row0 + 0) * 128 + j] = fmaxf(a0 + bj, 0.0f);
  out[(size_t)(row0 + 1) * 128 + j] = fmaxf(a1 + bj, 0.0f);
  out[(size_t)(row0 + 2) * 128 + j] = fmaxf(a2 + bj, 0.0f);
  out[(size_t)(row0 + 3) * 128 + j] = fmaxf(a3 + bj, 0.0f);
}

extern "C" void kernel_launch(void* const* d_in, const int* in_sizes, int n_in,
                              void* d_out, int out_size, void* d_ws, size_t ws_size,
                              hipStream_t stream) {
  const float* x    = (const float*)d_in[0];
  const int*   src0 = (const int*)d_in[1];
  const int*   dst0 = (const int*)d_in[2];
  const float* ew0  = (const float*)d_in[3];
  const int*   src1 = (const int*)d_in[4];
  const int*   dst1 = (const int*)d_in[5];
  const float* ew1  = (const float*)d_in[6];
  const float* W1   = (const float*)d_in[7];
  const float* b1   = (const float*)d_in[8];
  const float* W2   = (const float*)d_in[9];
  const float* b2   = (const float*)d_in[10];
  float* out = (float*)d_out;

  int*   wsi = (int*)d_ws;
  float* wsf = (float*)d_ws;
  int* outdeg0 = wsi + OFF_OUTDEG0I;
  int* outdeg1 = wsi + OFF_OUTDEG1I;
  int* cnt0    = wsi + OFF_CNT0;
  int* cnt1    = wsi + OFF_CNT1;
  int2* edge0  = (int2*)(wsi + OFF_EDGE0);
  int2* edge1  = (int2*)(wsi + OFF_EDGE1);
  float* h1    = wsf + OFF_H1;
  _Float16* w1t = (_Float16*)(wsi + OFF_W1T);
  _Float16* g   = (_Float16*)(wsi + OFF_G);

  k_zero<<<128, 256, 0, stream>>>((int4*)d_ws, ZERO_WORDS / 4);
  k_prep<<<32, 256, 0, stream>>>(W1, w1t);
  k_build<<<1024, 256, 0, stream>>>(src0, dst0, ew0, outdeg0, cnt0, edge0,
                                    src1, dst1, ew1, outdeg1, cnt1, edge1);
  k_gemm1<<<GEMM_GRID, 256, 0, stream>>>(x, outdeg0, w1t, g);
  k_gather1<<<(ND0 * 64) / 256, 256, 0, stream>>>(g, cnt0, edge0, outdeg1, b1, h1);
  k_layer2<<<ND1 / 8, 256, 0, stream>>>(h1, cnt1, edge1, W2, b2, out);
}

// Round 13
// 235.703 us; speedup vs baseline: 1.3960x; 1.0195x over previous
//
#include <hip/hip_runtime.h>

// Problem sizes (match reference)
#define NS0 300000
#define ND0 50000
#define NE0 800000
#define NS1 50000
#define ND1 8192
#define NE1 131072
#define IN_F 256
#define HID_F 128
#define SLOTS 64   // bucket-CSR capacity; indeg ~ Poisson(16), P(>=64) ~ 1e-19
#define NTILE (NS0 / 16)  // 18750 row-tiles for the dense GEMM
#define GEMM_GRID 2048
#define BUILD_GRID 512

typedef __attribute__((ext_vector_type(8))) _Float16 half8_t;
typedef __attribute__((ext_vector_type(4))) _Float16 half4_t;
typedef __attribute__((ext_vector_type(4))) float f32x4;

// Workspace layout (4-byte words), all 16B-aligned:
#define OFF_OUTDEG0I 0
#define OFF_OUTDEG1I 300000
#define OFF_CNT0     350000
#define OFF_CNT1     400000
#define ZERO_WORDS   408192
#define OFF_EDGE0    408192
#define OFF_EDGE1    6808192
#define OFF_H1       7856768
#define OFF_W1T      14256768
#define OFF_G        14273152

// ---------------- init: blocks [0,128) zero counters; [128,160) cvt W1->w1t
__global__ __launch_bounds__(256) void k_init(
    int4* __restrict__ p, const float* __restrict__ W1,
    _Float16* __restrict__ w1t) {
  if (blockIdx.x < 128) {
    int i = blockIdx.x * 256 + threadIdx.x;
    for (; i < ZERO_WORDS / 4; i += 128 * 256) p[i] = make_int4(0, 0, 0, 0);
  } else {
    int i = (blockIdx.x - 128) * 256 + threadIdx.x;
    for (; i < IN_F * HID_F; i += 32 * 256) {
      int k = i >> 7, n = i & 127;
      w1t[n * 256 + k] = (_Float16)W1[i];
    }
  }
}

// ---------------- fused: blocks [0, GEMM_GRID) dense GEMM g = x @ W1 (fp16
// MFMA, UNSCALED: outdeg0 norm moved to the gather coefficient, removing the
// build->gemm dependency); blocks [GEMM_GRID, +BUILD_GRID) run the edge build
// (degree histograms + bucket-CSR scatter) concurrently.
#define LDB(p, o) (*reinterpret_cast<const half8_t*>((p) + (o)))
__global__ __launch_bounds__(256) void k_gemm_build(
    const float* __restrict__ x, const _Float16* __restrict__ w1t,
    _Float16* __restrict__ g,
    const int* __restrict__ src0, const int* __restrict__ dst0,
    const float* __restrict__ ew0, int* __restrict__ outdeg0,
    int* __restrict__ cnt0, int2* __restrict__ edge0,
    const int* __restrict__ src1, const int* __restrict__ dst1,
    const float* __restrict__ ew1, int* __restrict__ outdeg1,
    int* __restrict__ cnt1, int2* __restrict__ edge1) {
  __shared__ __align__(16) _Float16 ldsA[2][16 * 256];  // 2 x 8KB, frag-order
  __shared__ _Float16 ldsT[4][16 * 40];                  // epilogue transpose

  if (blockIdx.x >= GEMM_GRID) {
    // ---------------- build path ----------------
    int tid = (blockIdx.x - GEMM_GRID) * 256 + threadIdx.x;
    int stride = BUILD_GRID * 256;
    for (int i = tid; i < NE0; i += stride) {
      int s = src0[i];
      int d = dst0[i];
      float w = ew0[i];
      atomicAdd(&outdeg0[s], 1);
      int slot = atomicAdd(&cnt0[d], 1);
      if (slot < SLOTS) edge0[d * SLOTS + slot] = make_int2(s, __float_as_int(w));
    }
    for (int i = tid; i < NE1; i += stride) {
      int s = src1[i];
      int d = dst1[i];
      float w = ew1[i];
      atomicAdd(&outdeg1[s], 1);
      int slot = atomicAdd(&cnt1[d], 1);
      if (slot < SLOTS) edge1[d * SLOTS + slot] = make_int2(s, __float_as_int(w));
    }
    return;
  }

  // ---------------- GEMM path ----------------
  const int tid = threadIdx.x;
  const int wv = tid >> 6;
  const int lane = tid & 63;
  const int m = lane & 15;
  const int grp = lane >> 4;
  _Float16* tp = ldsT[wv];

  // B-frag: lane holds W1[k = kb*32 + grp*8 + j][n = 32wv + 16c + m]
  const _Float16* wb0 = w1t + (size_t)(32 * wv + m) * 256 + grp * 8;
  const _Float16* wb1 = wb0 + 16 * 256;
  const half8_t b00 = LDB(wb0, 0),   b01 = LDB(wb0, 32),  b02 = LDB(wb0, 64),
                b03 = LDB(wb0, 96),  b04 = LDB(wb0, 128), b05 = LDB(wb0, 160),
                b06 = LDB(wb0, 192), b07 = LDB(wb0, 224);
  const half8_t b10 = LDB(wb1, 0),   b11 = LDB(wb1, 32),  b12 = LDB(wb1, 64),
                b13 = LDB(wb1, 96),  b14 = LDB(wb1, 128), b15 = LDB(wb1, 160),
                b16 = LDB(wb1, 192), b17 = LDB(wb1, 224);

  // staging constants (swizzle S = idx ^ skb ^ sgrp; conflict-free both sides)
  const int skb = lane >> 3;
  const int sgrp = (lane >> 1) & 3;
  const int sjh = lane & 1;
  const int row_r = lane >> 2;
  const int q_r   = lane & 3;

  const int bid = blockIdx.x;
  float4 pv[4];

  // prologue: stage tile bid into buf 0
  {
    const float* tb = x + (size_t)bid * 4096;
#pragma unroll
    for (int r = 0; r < 4; ++r) {
      const int mr = wv + 4 * r;
      const float4 v = *reinterpret_cast<const float4*>(tb + tid * 4 + r * 1024);
      half4_t h;
      h[0] = (_Float16)v.x; h[1] = (_Float16)v.y;
      h[2] = (_Float16)v.z; h[3] = (_Float16)v.w;
      const int idx = skb * 64 + sgrp * 16 + mr;
      const int S = idx ^ skb ^ sgrp;
      *reinterpret_cast<half4_t*>(
          reinterpret_cast<char*>(&ldsA[0][0]) + S * 16 + sjh * 8) = h;
    }
  }
  __syncthreads();

  int cur = 0;
  for (int tile = bid; tile < NTILE; tile += GEMM_GRID) {
    const int nxt = tile + GEMM_GRID;
    if (nxt < NTILE) {
      const float* tb = x + (size_t)nxt * 4096;
#pragma unroll
      for (int r = 0; r < 4; ++r)
        pv[r] = *reinterpret_cast<const float4*>(tb + tid * 4 + r * 1024);
    }
    {
      const char* A = reinterpret_cast<const char*>(&ldsA[cur][0]);
      f32x4 acc0 = {0.f, 0.f, 0.f, 0.f};
      f32x4 acc1 = {0.f, 0.f, 0.f, 0.f};
#define STEP(KB, B0, B1)                                                       \
  {                                                                            \
    const int Sr = ((KB * 64 + lane) ^ KB ^ grp);                              \
    const half8_t af = *reinterpret_cast<const half8_t*>(A + Sr * 16);         \
    acc0 = __builtin_amdgcn_mfma_f32_16x16x32_f16(af, B0, acc0, 0, 0, 0);      \
    acc1 = __builtin_amdgcn_mfma_f32_16x16x32_f16(af, B1, acc1, 0, 0, 0);      \
  }
      STEP(0, b00, b10)
      STEP(1, b01, b11)
      STEP(2, b02, b12)
      STEP(3, b03, b13)
      STEP(4, b04, b14)
      STEP(5, b05, b15)
      STEP(6, b06, b16)
      STEP(7, b07, b17)
#undef STEP
#pragma unroll
      for (int r = 0; r < 4; ++r) {
        tp[(4 * grp + r) * 40 + m]      = (_Float16)acc0[r];
        tp[(4 * grp + r) * 40 + 16 + m] = (_Float16)acc1[r];
      }
      const half8_t ov =
          *reinterpret_cast<const half8_t*>(tp + row_r * 40 + q_r * 8);
      *reinterpret_cast<half8_t*>(
          g + (size_t)(tile * 16 + row_r) * 128 + 32 * wv + q_r * 8) = ov;
    }
    if (nxt < NTILE) {
      char* B = reinterpret_cast<char*>(&ldsA[cur ^ 1][0]);
#pragma unroll
      for (int r = 0; r < 4; ++r) {
        const int mr = wv + 4 * r;
        half4_t h;
        h[0] = (_Float16)pv[r].x; h[1] = (_Float16)pv[r].y;
        h[2] = (_Float16)pv[r].z; h[3] = (_Float16)pv[r].w;
        const int idx = skb * 64 + sgrp * 16 + mr;
        const int S = idx ^ skb ^ sgrp;
        *reinterpret_cast<half4_t*>(B + S * 16 + sjh * 8) = h;
      }
    }
    __syncthreads();
    cur ^= 1;
  }
}

// ---------------- layer-1 aggregation over g (fp16, 77 MB, L3-resident):
// h1[d] = relu(rsqrt(indeg)*sum ew*rsqrt(outdeg0[src])*g[src] + b1) * rsqrt(outdeg1[d])
__global__ __launch_bounds__(256) void k_gather1(
    const _Float16* __restrict__ g, const int* __restrict__ cnt,
    const int2* __restrict__ edge, const int* __restrict__ outdeg0,
    const int* __restrict__ outdeg1, const float* __restrict__ b1,
    float* __restrict__ h1) {
  const int w = (blockIdx.x * 256 + threadIdx.x) >> 6;  // dst row
  const int lane = threadIdx.x & 63;
  const int gp = lane >> 4;
  const int sl = lane & 15;
  if (w >= ND0) return;
  const int deg = min(cnt[w], SLOTS);
  const int2* ep = edge + (size_t)w * SLOTS;
  float acc[8] = {0.f, 0.f, 0.f, 0.f, 0.f, 0.f, 0.f, 0.f};
  for (int e = 0; e < deg; e += 4) {
    const int idx = e + gp;
    int2 p = make_int2(0, 0);
    float c = 0.f;
    if (idx < deg) {
      p = ep[idx];
      c = __int_as_float(p.y) * rsqrtf(fmaxf((float)outdeg0[p.x], 1.0f));
    }
    const half8_t v =
        *reinterpret_cast<const half8_t*>(g + (size_t)p.x * 128 + sl * 8);
#pragma unroll
    for (int j = 0; j < 8; ++j) acc[j] = fmaf(c, (float)v[j], acc[j]);
  }
#pragma unroll
  for (int j = 0; j < 8; ++j) {
    acc[j] += __shfl_xor(acc[j], 16, 64);
    acc[j] += __shfl_xor(acc[j], 32, 64);
  }
  if (gp == 0) {
    const float sc = rsqrtf(fmaxf((float)deg, 1.0f));
    const float s1 = rsqrtf(fmaxf((float)outdeg1[w], 1.0f));
    const float4 bv0 = *reinterpret_cast<const float4*>(b1 + sl * 8);
    const float4 bv1 = *reinterpret_cast<const float4*>(b1 + sl * 8 + 4);
    float4 o0, o1;
    o0.x = fmaxf(fmaf(acc[0], sc, bv0.x), 0.0f) * s1;
    o0.y = fmaxf(fmaf(acc[1], sc, bv0.y), 0.0f) * s1;
    o0.z = fmaxf(fmaf(acc[2], sc, bv0.z), 0.0f) * s1;
    o0.w = fmaxf(fmaf(acc[3], sc, bv0.w), 0.0f) * s1;
    o1.x = fmaxf(fmaf(acc[4], sc, bv1.x), 0.0f) * s1;
    o1.y = fmaxf(fmaf(acc[5], sc, bv1.y), 0.0f) * s1;
    o1.z = fmaxf(fmaf(acc[6], sc, bv1.z), 0.0f) * s1;
    o1.w = fmaxf(fmaf(acc[7], sc, bv1.w), 0.0f) * s1;
    float* hr = h1 + (size_t)w * 128 + sl * 8;
    *reinterpret_cast<float4*>(hr) = o0;
    *reinterpret_cast<float4*>(hr + 4) = o1;
  }
}

#define FMA2(acc, c, v)        \
  acc.x = fmaf(c, v.x, acc.x); \
  acc.y = fmaf(c, v.y, acc.y);

// --------------------------------------------- fused gather + GEMM, layer 2
__global__ __launch_bounds__(256) void k_layer2(
    const float* __restrict__ h1, const int* __restrict__ cnt,
    const int2* __restrict__ edge, const float* __restrict__ W2,
    const float* __restrict__ b2, float* __restrict__ out) {
  __shared__ float arow[8][HID_F];
  const int t = blockIdx.x;
  const int wv = threadIdx.x >> 6;
  const int lane = threadIdx.x & 63;

#pragma unroll
  for (int rr = 0; rr < 2; ++rr) {
    const int row = t * 8 + wv * 2 + rr;
    const int deg = min(cnt[row], SLOTS);
    const int2* ep = edge + (size_t)row * SLOTS;
    float2 acc = make_float2(0.f, 0.f);
    int e = 0;
    for (; e + 4 <= deg; e += 4) {
      int4 q0 = *reinterpret_cast<const int4*>(ep + e);
      int4 q1 = *reinterpret_cast<const int4*>(ep + e + 2);
      float2 v0 = *reinterpret_cast<const float2*>(h1 + (size_t)q0.x * HID_F + lane * 2);
      float2 v1 = *reinterpret_cast<const float2*>(h1 + (size_t)q0.z * HID_F + lane * 2);
      float2 v2 = *reinterpret_cast<const float2*>(h1 + (size_t)q1.x * HID_F + lane * 2);
      float2 v3 = *reinterpret_cast<const float2*>(h1 + (size_t)q1.z * HID_F + lane * 2);
      FMA2(acc, __int_as_float(q0.y), v0);
      FMA2(acc, __int_as_float(q0.w), v1);
      FMA2(acc, __int_as_float(q1.y), v2);
      FMA2(acc, __int_as_float(q1.w), v3);
    }
    for (; e < deg; ++e) {
      int2 p = ep[e];
      float2 v = *reinterpret_cast<const float2*>(h1 + (size_t)p.x * HID_F + lane * 2);
      FMA2(acc, __int_as_float(p.y), v);
    }
    const float sc = rsqrtf(fmaxf((float)deg, 1.0f));
    *reinterpret_cast<float2*>(&arow[wv * 2 + rr][lane * 2]) =
        make_float2(acc.x * sc, acc.y * sc);
  }
  __syncthreads();

  const int j = threadIdx.x & 127;
  const int rg = threadIdx.x >> 7;
  float a0 = 0.f, a1 = 0.f, a2 = 0.f, a3 = 0.f;
  const float* wj = W2 + j;
#pragma unroll 8
  for (int k = 0; k < HID_F; ++k) {
    const float wvv = wj[(size_t)k * 128];
    a0 = fmaf(arow[rg * 4 + 0][k], wvv, a0);
    a1 = fmaf(arow[rg * 4 + 1][k], wvv, a1);
    a2 = fmaf(arow[rg * 4 + 2][k], wvv, a2);
    a3 = fmaf(arow[rg * 4 + 3][k], wvv, a3);
  }
  const float bj = b2[j];
  const int row0 = t * 8 + rg * 4;
  out[(size_t)(row0 + 0) * 128 + j] = fmaxf(a0 + bj, 0.0f);
  out[(size_t)(row0 + 1) * 128 + j] = fmaxf(a1 + bj, 0.0f);
  out[(size_t)(row0 + 2) * 128 + j] = fmaxf(a2 + bj, 0.0f);
  out[(size_t)(row0 + 3) * 128 + j] = fmaxf(a3 + bj, 0.0f);
}

extern "C" void kernel_launch(void* const* d_in, const int* in_sizes, int n_in,
                              void* d_out, int out_size, void* d_ws, size_t ws_size,
                              hipStream_t stream) {
  const float* x    = (const float*)d_in[0];
  const int*   src0 = (const int*)d_in[1];
  const int*   dst0 = (const int*)d_in[2];
  const float* ew0  = (const float*)d_in[3];
  const int*   src1 = (const int*)d_in[4];
  const int*   dst1 = (const int*)d_in[5];
  const float* ew1  = (const float*)d_in[6];
  const float* W1   = (const float*)d_in[7];
  const float* b1   = (const float*)d_in[8];
  const float* W2   = (const float*)d_in[9];
  const float* b2   = (const float*)d_in[10];
  float* out = (float*)d_out;

  int*   wsi = (int*)d_ws;
  float* wsf = (float*)d_ws;
  int* outdeg0 = wsi + OFF_OUTDEG0I;
  int* outdeg1 = wsi + OFF_OUTDEG1I;
  int* cnt0    = wsi + OFF_CNT0;
  int* cnt1    = wsi + OFF_CNT1;
  int2* edge0  = (int2*)(wsi + OFF_EDGE0);
  int2* edge1  = (int2*)(wsi + OFF_EDGE1);
  float* h1    = wsf + OFF_H1;
  _Float16* w1t = (_Float16*)(wsi + OFF_W1T);
  _Float16* g   = (_Float16*)(wsi + OFF_G);

  k_init<<<160, 256, 0, stream>>>((int4*)d_ws, W1, w1t);
  k_gemm_build<<<GEMM_GRID + BUILD_GRID, 256, 0, stream>>>(
      x, w1t, g, src0, dst0, ew0, outdeg0, cnt0, edge0,
      src1, dst1, ew1, outdeg1, cnt1, edge1);
  k_gather1<<<(ND0 * 64) / 256, 256, 0, stream>>>(g, cnt0, edge0, outdeg0,
                                                  outdeg1, b1, h1);
  k_layer2<<<ND1 / 8, 256, 0, stream>>>(h1, cnt1, edge1, W2, b2, out);
}

// Round 14
// 228.938 us; speedup vs baseline: 1.4372x; 1.0296x over previous
//
#include <hip/hip_runtime.h>

// Problem sizes (match reference)
#define NS0 300000
#define ND0 50000
#define NE0 800000
#define NS1 50000
#define ND1 8192
#define NE1 131072
#define IN_F 256
#define HID_F 128
#define SLOTS 64   // bucket-CSR capacity; indeg ~ Poisson(16), P(>=64) ~ 1e-19
#define NTILE (NS0 / 16)  // 18750 row-tiles for the dense GEMM
#define GEMM_GRID 2048
#define BUILD_GRID 512

typedef __attribute__((ext_vector_type(8))) _Float16 half8_t;
typedef __attribute__((ext_vector_type(4))) _Float16 half4_t;
typedef __attribute__((ext_vector_type(4))) float f32x4;

// Workspace layout (4-byte words), all 16B-aligned:
#define OFF_OUTDEG0I 0
#define OFF_OUTDEG1I 300000
#define OFF_CNT0     350000
#define OFF_CNT1     400000
#define ZERO_WORDS   408192
#define OFF_EDGE0    408192
#define OFF_EDGE1    6808192
#define OFF_H1       7856768
#define OFF_W1T      14256768
#define OFF_G        14273152

// ---------------- init: blocks [0,128) zero counters; [128,160) cvt W1->w1t
__global__ __launch_bounds__(256) void k_init(
    int4* __restrict__ p, const float* __restrict__ W1,
    _Float16* __restrict__ w1t) {
  if (blockIdx.x < 128) {
    int i = blockIdx.x * 256 + threadIdx.x;
    for (; i < ZERO_WORDS / 4; i += 128 * 256) p[i] = make_int4(0, 0, 0, 0);
  } else {
    int i = (blockIdx.x - 128) * 256 + threadIdx.x;
    for (; i < IN_F * HID_F; i += 32 * 256) {
      int k = i >> 7, n = i & 127;
      w1t[n * 256 + k] = (_Float16)W1[i];
    }
  }
}

// ---------------- fused: blocks [0, BUILD_GRID) run the edge build FIRST
// (round-13 post-mortem: build blocks placed after the persistent GEMM blocks
// were scheduled last -> zero overlap; build must be in the first dispatch
// wave). Blocks [BUILD_GRID, +GEMM_GRID) run the dense GEMM g = x @ W1
// (fp16 MFMA, unscaled; outdeg0 norm applied at gather). 2-deep load
// pipeline: loads issued 2 tiles ahead so the LDS-write never waits on HBM.
#define LDB(p, o) (*reinterpret_cast<const half8_t*>((p) + (o)))
__global__ __launch_bounds__(256) void k_gemm_build(
    const float* __restrict__ x, const _Float16* __restrict__ w1t,
    _Float16* __restrict__ g,
    const int* __restrict__ src0, const int* __restrict__ dst0,
    const float* __restrict__ ew0, int* __restrict__ outdeg0,
    int* __restrict__ cnt0, int2* __restrict__ edge0,
    const int* __restrict__ src1, const int* __restrict__ dst1,
    const float* __restrict__ ew1, int* __restrict__ outdeg1,
    int* __restrict__ cnt1, int2* __restrict__ edge1) {
  __shared__ __align__(16) _Float16 ldsA[2][16 * 256];  // 2 x 8KB, frag-order
  __shared__ _Float16 ldsT[4][16 * 40];                  // epilogue transpose

  if (blockIdx.x < BUILD_GRID) {
    // ---------------- build path (first scheduling wave) ----------------
    int tid = blockIdx.x * 256 + threadIdx.x;
    int stride = BUILD_GRID * 256;
    for (int i = tid; i < NE0; i += stride) {
      int s = src0[i];
      int d = dst0[i];
      float w = ew0[i];
      atomicAdd(&outdeg0[s], 1);
      int slot = atomicAdd(&cnt0[d], 1);
      if (slot < SLOTS) edge0[d * SLOTS + slot] = make_int2(s, __float_as_int(w));
    }
    for (int i = tid; i < NE1; i += stride) {
      int s = src1[i];
      int d = dst1[i];
      float w = ew1[i];
      atomicAdd(&outdeg1[s], 1);
      int slot = atomicAdd(&cnt1[d], 1);
      if (slot < SLOTS) edge1[d * SLOTS + slot] = make_int2(s, __float_as_int(w));
    }
    return;
  }

  // ---------------- GEMM path ----------------
  const int tid = threadIdx.x;
  const int wv = tid >> 6;
  const int lane = tid & 63;
  const int m = lane & 15;
  const int grp = lane >> 4;
  _Float16* tp = ldsT[wv];

  // B-frag: lane holds W1[k = kb*32 + grp*8 + j][n = 32wv + 16c + m]
  const _Float16* wb0 = w1t + (size_t)(32 * wv + m) * 256 + grp * 8;
  const _Float16* wb1 = wb0 + 16 * 256;
  const half8_t b00 = LDB(wb0, 0),   b01 = LDB(wb0, 32),  b02 = LDB(wb0, 64),
                b03 = LDB(wb0, 96),  b04 = LDB(wb0, 128), b05 = LDB(wb0, 160),
                b06 = LDB(wb0, 192), b07 = LDB(wb0, 224);
  const half8_t b10 = LDB(wb1, 0),   b11 = LDB(wb1, 32),  b12 = LDB(wb1, 64),
                b13 = LDB(wb1, 96),  b14 = LDB(wb1, 128), b15 = LDB(wb1, 160),
                b16 = LDB(wb1, 192), b17 = LDB(wb1, 224);

  // staging constants (swizzle S = idx ^ skb ^ sgrp; conflict-free both sides)
  const int skb = lane >> 3;
  const int sgrp = (lane >> 1) & 3;
  const int sjh = lane & 1;
  const int row_r = lane >> 2;
  const int q_r   = lane & 3;

  const int bid = blockIdx.x - BUILD_GRID;
  float4 pvA[4], pvB[4];

  // prologue: stage tile bid into buf 0 directly; issue loads for bid+G
  {
    const float* tb = x + (size_t)bid * 4096;
#pragma unroll
    for (int r = 0; r < 4; ++r) {
      const int mr = wv + 4 * r;
      const float4 v = *reinterpret_cast<const float4*>(tb + tid * 4 + r * 1024);
      half4_t h;
      h[0] = (_Float16)v.x; h[1] = (_Float16)v.y;
      h[2] = (_Float16)v.z; h[3] = (_Float16)v.w;
      const int idx = skb * 64 + sgrp * 16 + mr;
      const int S = idx ^ skb ^ sgrp;
      *reinterpret_cast<half4_t*>(
          reinterpret_cast<char*>(&ldsA[0][0]) + S * 16 + sjh * 8) = h;
    }
  }
  if (bid + GEMM_GRID < NTILE) {
    const float* tb = x + (size_t)(bid + GEMM_GRID) * 4096;
#pragma unroll
    for (int r = 0; r < 4; ++r)
      pvA[r] = *reinterpret_cast<const float4*>(tb + tid * 4 + r * 1024);
  }
  __syncthreads();

  int cur = 0;
  for (int tile = bid; tile < NTILE; tile += GEMM_GRID) {
    const int tnext = tile + GEMM_GRID;
    const int tnext2 = tile + 2 * GEMM_GRID;
    // (a) issue loads two tiles ahead
    if (tnext2 < NTILE) {
      const float* tb = x + (size_t)tnext2 * 4096;
#pragma unroll
      for (int r = 0; r < 4; ++r)
        pvB[r] = *reinterpret_cast<const float4*>(tb + tid * 4 + r * 1024);
    }
    // (b) compute current tile from LDS
    {
      const char* A = reinterpret_cast<const char*>(&ldsA[cur][0]);
      f32x4 acc0 = {0.f, 0.f, 0.f, 0.f};
      f32x4 acc1 = {0.f, 0.f, 0.f, 0.f};
#define STEP(KB, B0, B1)                                                       \
  {                                                                            \
    const int Sr = ((KB * 64 + lane) ^ KB ^ grp);                              \
    const half8_t af = *reinterpret_cast<const half8_t*>(A + Sr * 16);         \
    acc0 = __builtin_amdgcn_mfma_f32_16x16x32_f16(af, B0, acc0, 0, 0, 0);      \
    acc1 = __builtin_amdgcn_mfma_f32_16x16x32_f16(af, B1, acc1, 0, 0, 0);      \
  }
      STEP(0, b00, b10)
      STEP(1, b01, b11)
      STEP(2, b02, b12)
      STEP(3, b03, b13)
      STEP(4, b04, b14)
      STEP(5, b05, b15)
      STEP(6, b06, b16)
      STEP(7, b07, b17)
#undef STEP
#pragma unroll
      for (int r = 0; r < 4; ++r) {
        tp[(4 * grp + r) * 40 + m]      = (_Float16)acc0[r];
        tp[(4 * grp + r) * 40 + 16 + m] = (_Float16)acc1[r];
      }
      const half8_t ov =
          *reinterpret_cast<const half8_t*>(tp + row_r * 40 + q_r * 8);
      *reinterpret_cast<half8_t*>(
          g + (size_t)(tile * 16 + row_r) * 128 + 32 * wv + q_r * 8) = ov;
    }
    // (c) write tile+G (loaded LAST iteration -> already landed) into buf^1
    if (tnext < NTILE) {
      char* B = reinterpret_cast<char*>(&ldsA[cur ^ 1][0]);
#pragma unroll
      for (int r = 0; r < 4; ++r) {
        const int mr = wv + 4 * r;
        half4_t h;
        h[0] = (_Float16)pvA[r].x; h[1] = (_Float16)pvA[r].y;
        h[2] = (_Float16)pvA[r].z; h[3] = (_Float16)pvA[r].w;
        const int idx = skb * 64 + sgrp * 16 + mr;
        const int S = idx ^ skb ^ sgrp;
        *reinterpret_cast<half4_t*>(B + S * 16 + sjh * 8) = h;
      }
    }
    // (d) one barrier per tile; rotate register pipeline
    __syncthreads();
    cur ^= 1;
#pragma unroll
    for (int r = 0; r < 4; ++r) pvA[r] = pvB[r];
  }
}

// ---------------- layer-1 aggregation over g (fp16, 77 MB, L3-resident):
// h1[d] = relu(rsqrt(indeg)*sum ew*rsqrt(outdeg0[src])*g[src] + b1) * rsqrt(outdeg1[d])
__global__ __launch_bounds__(256) void k_gather1(
    const _Float16* __restrict__ g, const int* __restrict__ cnt,
    const int2* __restrict__ edge, const int* __restrict__ outdeg0,
    const int* __restrict__ outdeg1, const float* __restrict__ b1,
    float* __restrict__ h1) {
  const int w = (blockIdx.x * 256 + threadIdx.x) >> 6;  // dst row
  const int lane = threadIdx.x & 63;
  const int gp = lane >> 4;
  const int sl = lane & 15;
  if (w >= ND0) return;
  const int deg = min(cnt[w], SLOTS);
  const int2* ep = edge + (size_t)w * SLOTS;
  float acc[8] = {0.f, 0.f, 0.f, 0.f, 0.f, 0.f, 0.f, 0.f};
  for (int e = 0; e < deg; e += 4) {
    const int idx = e + gp;
    int2 p = make_int2(0, 0);
    float c = 0.f;
    if (idx < deg) {
      p = ep[idx];
      c = __int_as_float(p.y) * rsqrtf(fmaxf((float)outdeg0[p.x], 1.0f));
    }
    const half8_t v =
        *reinterpret_cast<const half8_t*>(g + (size_t)p.x * 128 + sl * 8);
#pragma unroll
    for (int j = 0; j < 8; ++j) acc[j] = fmaf(c, (float)v[j], acc[j]);
  }
#pragma unroll
  for (int j = 0; j < 8; ++j) {
    acc[j] += __shfl_xor(acc[j], 16, 64);
    acc[j] += __shfl_xor(acc[j], 32, 64);
  }
  if (gp == 0) {
    const float sc = rsqrtf(fmaxf((float)deg, 1.0f));
    const float s1 = rsqrtf(fmaxf((float)outdeg1[w], 1.0f));
    const float4 bv0 = *reinterpret_cast<const float4*>(b1 + sl * 8);
    const float4 bv1 = *reinterpret_cast<const float4*>(b1 + sl * 8 + 4);
    float4 o0, o1;
    o0.x = fmaxf(fmaf(acc[0], sc, bv0.x), 0.0f) * s1;
    o0.y = fmaxf(fmaf(acc[1], sc, bv0.y), 0.0f) * s1;
    o0.z = fmaxf(fmaf(acc[2], sc, bv0.z), 0.0f) * s1;
    o0.w = fmaxf(fmaf(acc[3], sc, bv0.w), 0.0f) * s1;
    o1.x = fmaxf(fmaf(acc[4], sc, bv1.x), 0.0f) * s1;
    o1.y = fmaxf(fmaf(acc[5], sc, bv1.y), 0.0f) * s1;
    o1.z = fmaxf(fmaf(acc[6], sc, bv1.z), 0.0f) * s1;
    o1.w = fmaxf(fmaf(acc[7], sc, bv1.w), 0.0f) * s1;
    float* hr = h1 + (size_t)w * 128 + sl * 8;
    *reinterpret_cast<float4*>(hr) = o0;
    *reinterpret_cast<float4*>(hr + 4) = o1;
  }
}

#define FMA2(acc, c, v)        \
  acc.x = fmaf(c, v.x, acc.x); \
  acc.y = fmaf(c, v.y, acc.y);

// --------------------------------------------- fused gather + GEMM, layer 2
__global__ __launch_bounds__(256) void k_layer2(
    const float* __restrict__ h1, const int* __restrict__ cnt,
    const int2* __restrict__ edge, const float* __restrict__ W2,
    const float* __restrict__ b2, float* __restrict__ out) {
  __shared__ float arow[8][HID_F];
  const int t = blockIdx.x;
  const int wv = threadIdx.x >> 6;
  const int lane = threadIdx.x & 63;

#pragma unroll
  for (int rr = 0; rr < 2; ++rr) {
    const int row = t * 8 + wv * 2 + rr;
    const int deg = min(cnt[row], SLOTS);
    const int2* ep = edge + (size_t)row * SLOTS;
    float2 acc = make_float2(0.f, 0.f);
    int e = 0;
    for (; e + 4 <= deg; e += 4) {
      int4 q0 = *reinterpret_cast<const int4*>(ep + e);
      int4 q1 = *reinterpret_cast<const int4*>(ep + e + 2);
      float2 v0 = *reinterpret_cast<const float2*>(h1 + (size_t)q0.x * HID_F + lane * 2);
      float2 v1 = *reinterpret_cast<const float2*>(h1 + (size_t)q0.z * HID_F + lane * 2);
      float2 v2 = *reinterpret_cast<const float2*>(h1 + (size_t)q1.x * HID_F + lane * 2);
      float2 v3 = *reinterpret_cast<const float2*>(h1 + (size_t)q1.z * HID_F + lane * 2);
      FMA2(acc, __int_as_float(q0.y), v0);
      FMA2(acc, __int_as_float(q0.w), v1);
      FMA2(acc, __int_as_float(q1.y), v2);
      FMA2(acc, __int_as_float(q1.w), v3);
    }
    for (; e < deg; ++e) {
      int2 p = ep[e];
      float2 v = *reinterpret_cast<const float2*>(h1 + (size_t)p.x * HID_F + lane * 2);
      FMA2(acc, __int_as_float(p.y), v);
    }
    const float sc = rsqrtf(fmaxf((float)deg, 1.0f));
    *reinterpret_cast<float2*>(&arow[wv * 2 + rr][lane * 2]) =
        make_float2(acc.x * sc, acc.y * sc);
  }
  __syncthreads();

  const int j = threadIdx.x & 127;
  const int rg = threadIdx.x >> 7;
  float a0 = 0.f, a1 = 0.f, a2 = 0.f, a3 = 0.f;
  const float* wj = W2 + j;
#pragma unroll 8
  for (int k = 0; k < HID_F; ++k) {
    const float wvv = wj[(size_t)k * 128];
    a0 = fmaf(arow[rg * 4 + 0][k], wvv, a0);
    a1 = fmaf(arow[rg * 4 + 1][k], wvv, a1);
    a2 = fmaf(arow[rg * 4 + 2][k], wvv, a2);
    a3 = fmaf(arow[rg * 4 + 3][k], wvv, a3);
  }
  const float bj = b2[j];
  const int row0 = t * 8 + rg * 4;
  out[(size_t)(row0 + 0) * 128 + j] = fmaxf(a0 + bj, 0.0f);
  out[(size_t)(row0 + 1) * 128 + j] = fmaxf(a1 + bj, 0.0f);
  out[(size_t)(row0 + 2) * 128 + j] = fmaxf(a2 + bj, 0.0f);
  out[(size_t)(row0 + 3) * 128 + j] = fmaxf(a3 + bj, 0.0f);
}

extern "C" void kernel_launch(void* const* d_in, const int* in_sizes, int n_in,
                              void* d_out, int out_size, void* d_ws, size_t ws_size,
                              hipStream_t stream) {
  const float* x    = (const float*)d_in[0];
  const int*   src0 = (const int*)d_in[1];
  const int*   dst0 = (const int*)d_in[2];
  const float* ew0  = (const float*)d_in[3];
  const int*   src1 = (const int*)d_in[4];
  const int*   dst1 = (const int*)d_in[5];
  const float* ew1  = (const float*)d_in[6];
  const float* W1   = (const float*)d_in[7];
  const float* b1   = (const float*)d_in[8];
  const float* W2   = (const float*)d_in[9];
  const float* b2   = (const float*)d_in[10];
  float* out = (float*)d_out;

  int*   wsi = (int*)d_ws;
  float* wsf = (float*)d_ws;
  int* outdeg0 = wsi + OFF_OUTDEG0I;
  int* outdeg1 = wsi + OFF_OUTDEG1I;
  int* cnt0    = wsi + OFF_CNT0;
  int* cnt1    = wsi + OFF_CNT1;
  int2* edge0  = (int2*)(wsi + OFF_EDGE0);
  int2* edge1  = (int2*)(wsi + OFF_EDGE1);
  float* h1    = wsf + OFF_H1;
  _Float16* w1t = (_Float16*)(wsi + OFF_W1T);
  _Float16* g   = (_Float16*)(wsi + OFF_G);

  k_init<<<160, 256, 0, stream>>>((int4*)d_ws, W1, w1t);
  k_gemm_build<<<GEMM_GRID + BUILD_GRID, 256, 0, stream>>>(
      x, w1t, g, src0, dst0, ew0, outdeg0, cnt0, edge0,
      src1, dst1, ew1, outdeg1, cnt1, edge1);
  k_gather1<<<(ND0 * 64) / 256, 256, 0, stream>>>(g, cnt0, edge0, outdeg0,
                                                  outdeg1, b1, h1);
  k_layer2<<<ND1 / 8, 256, 0, stream>>>(h1, cnt1, edge1, W2, b2, out);
}